// Round 12
// baseline (258.452 us; speedup 1.0000x reference)
//
#include <hip/hip_runtime.h>
#include <stdint.h>

#define B_   8
#define D_   192      // Cin*3
#define N_   2048
#define KNb  11       // k+1

using u32 = uint32_t;
using u16 = unsigned short;
typedef _Float16 f16;
struct alignas(8) h4 { f16 x, y, z, w; };

typedef __attribute__((ext_vector_type(8)))  short short8;
typedef __attribute__((ext_vector_type(16))) float f32x16;

__device__ __forceinline__ u16 f2bf(float f){
  union{float f; u32 i;} x; x.f = f;
  u32 r = (x.i + 0x7fffu + ((x.i >> 16) & 1u)) >> 16;
  return (u16)r;
}
__device__ __forceinline__ u32 umax32(u32 a, u32 b){ return a > b ? a : b; }
__device__ __forceinline__ u32 umin32(u32 a, u32 b){ return a < b ? a : b; }

// branchless sorted-insert of 16 packed keys (read from ctp) into ascending key[10]
__device__ __forceinline__ void sel16(const u32* __restrict__ ctp, u32* key){
  #pragma unroll
  for (int q = 0; q < 4; ++q){
    uint4 kv = *(const uint4*)(ctp + 4*q);
    u32 ks[4] = {kv.x, kv.y, kv.z, kv.w};
    #pragma unroll
    for (int j = 0; j < 4; ++j){
      u32 kk = ks[j];
      #pragma unroll
      for (int s = 0; s < 9; ++s) key[s] = umin32(key[s+1], umax32(kk, key[s]));
      key[9] = umax32(kk, key[9]);
    }
  }
}

// ---------------- K0: bf16 fragment-page emit + fp32 transpose + f64 xx ----------------
// 32-pt tiles (24KB LDS) -> grid (64,8)=512 blocks = 2 blocks/CU.
// Xs layout: page P=(b*64+tile)*12+chunk, [lane][8 bf16] fragment order.
__global__ __launch_bounds__(256) void split_kernel(const float* __restrict__ x,
                                                    short* __restrict__ Xs,
                                                    float* __restrict__ xT,
                                                    double* __restrict__ xxd){
  __shared__ float A[D_ * 32];                       // 24 KB, [d][m]
  const int b = blockIdx.y, tile = blockIdx.x, m0 = tile * 32, t = threadIdx.x;
  const size_t xb = (size_t)b * D_ * N_;
  #pragma unroll
  for (int q = 0; q < 24; ++q){
    int p = t + 256*q;
    int d = p >> 5, i = p & 31;
    A[d*32 + i] = x[xb + (size_t)d*N_ + m0 + i];
  }
  __syncthreads();

  {
    const int l = t & 63, wv = t >> 6;
    const int lh = l >> 5, l31 = l & 31;
    #pragma unroll
    for (int j = 0; j < 3; ++j){
      int c = j*4 + wv;                  // chunk 0..11
      int dbase = c*16 + lh*8;
      union{ u16 s[8]; int4 v; } u;
      #pragma unroll
      for (int q = 0; q < 8; ++q) u.s[q] = f2bf(A[(dbase + q)*32 + l31]);
      size_t P = ((size_t)b*64 + tile)*12 + c;
      *(int4*)(Xs + P*512 + l*8) = u.v;
    }
  }
  {
    const int m = t & 31, seg = t >> 5;  // 8 segs of 24 d's
    float* trow = xT + ((size_t)b*N_ + m0 + m) * 192 + seg*24;
    #pragma unroll
    for (int j = 0; j < 6; ++j){
      float4 v = { A[(seg*24 + 4*j + 0)*32 + m], A[(seg*24 + 4*j + 1)*32 + m],
                   A[(seg*24 + 4*j + 2)*32 + m], A[(seg*24 + 4*j + 3)*32 + m] };
      *(float4*)(trow + 4*j) = v;
    }
  }
  if (t < 32){
    double s = 0.0;
    #pragma unroll 4
    for (int d = 0; d < D_; ++d){ double v = (double)A[d*32 + t]; s = fma(v, v, s); }
    xxd[b*N_ + m0 + t] = s;
  }
}

// ---------------- K1: MFMA kNN, full-stripe register prefetch ----------------
// R11 postmortem: occupancy ~8 waves/CU (2/SIMD) in every variant -> latency-bound,
// ~85% idle; R9's rolling 4-deep prefetch stalls the MFMA loop on L2 every 2 kc.
// Fix: all 12 B-pages -> pg[12] registers (48 VGPR) issued BEFORE sel16, so ~770cy
// of selection VALU covers the load flight; MFMA phase runs register-only.
#define KLA   0         // 12,288 : A pages
#define KLCT0 12288     // u32[32*260] = 33,280 (buffer 0; aliased by merge keys)
#define KLCT1 45568     // u32[32*260] = 33,280 (buffer 1)
#define KLSZ  78848
__global__ __launch_bounds__(512, 4) void knn_kernel(const short* __restrict__ Xs,
                                                     const double* __restrict__ xxd,
                                                     u16* __restrict__ cand){
  __shared__ __align__(16) char smem[KLSZ];

  const int b = blockIdx.x, n0 = blockIdx.y * 32;
  const int t = threadIdx.x, lane = t & 63, w = t >> 6;
  const int l31 = lane & 31, lh = lane >> 5;
  const int mcol = w*32 + l31;

  // stage A (12 pages = query tile n0>>5)
  {
    const short* Ap = Xs + (((size_t)b*64 + (n0 >> 5)) * 12) * 512;
    int4 v = *(const int4*)(Ap + (size_t)t*8);
    *(int4*)(smem + KLA + t*16) = v;
    if (t < 256){
      int p = t + 512;
      int4 v2 = *(const int4*)(Ap + (size_t)p*8);
      *(int4*)(smem + KLA + p*16) = v2;
    }
  }
  // query-row norms in registers (constant over stripes)
  float xxn[16];
  #pragma unroll
  for (int reg = 0; reg < 16; ++reg){
    int r = (reg & 3) + 8*(reg >> 2) + 4*lh;
    xxn[reg] = (float)xxd[b*N_ + n0 + r];
  }
  __syncthreads();                                 // A staged

  u32 key[10];
  #pragma unroll
  for (int j = 0; j < 10; ++j) key[j] = 0u;

  for (int st = 0; st < 8; ++st){
    const int m0 = st * 256;
    // wave w consumes neighbor tile st*8+w: issue ALL 12 page loads up front
    const short* Bp = Xs + (((size_t)b*64 + st*8 + w) * 12) * 512 + lane*8;
    short8 pg[12];
    #pragma unroll
    for (int j = 0; j < 12; ++j) pg[j] = *(const short8*)(Bp + j*512);
    float xxs = (float)xxd[b*N_ + m0 + mcol];

    // selection of previous stripe overlaps the load flight above
    if (st > 0){
      const u32* ctp = (const u32*)(smem + ((st & 1) ? KLCT0 : KLCT1))
                       + (t & 31)*260 + (t >> 5)*16;
      sel16(ctp, key);
    }

    f32x16 acc = (f32x16)0.0f;
    #pragma unroll
    for (int kc = 0; kc < 6; ++kc){
      short8 a0 = *(const short8*)(smem + KLA + (kc*2+0)*1024 + lane*16);
      short8 a1 = *(const short8*)(smem + KLA + (kc*2+1)*1024 + lane*16);
      acc = __builtin_amdgcn_mfma_f32_32x32x16_bf16(a0, pg[kc*2+0], acc, 0, 0, 0);
      acc = __builtin_amdgcn_mfma_f32_32x32x16_bf16(a1, pg[kc*2+1], acc, 0, 0, 0);
    }

    // pack keys in registers, write to this stripe's buffer
    {
      u32* ctw = (u32*)(smem + ((st & 1) ? KLCT1 : KLCT0));
      const u32 midx = (u32)(m0 + mcol);
      #pragma unroll
      for (int reg = 0; reg < 16; ++reg){
        float v = fmaf(2.f, acc[reg], -(xxs + xxn[reg]));
        u32 bb = __float_as_uint(v);
        u32 kk = ((bb ^ (u32)(((int)bb >> 31) | 0x80000000)) & 0xFFFFF800u) | midx;
        int r = (reg & 3) + 8*(reg >> 2) + 4*lh;
        ctw[r*260 + mcol] = kk;
      }
    }
    __syncthreads();                               // one barrier per stripe
  }
  // final stripe's selection (stripe 7 wrote KLCT1)
  {
    const u32* ctp = (const u32*)(smem + KLCT1) + (t & 31)*260 + (t >> 5)*16;
    sel16(ctp, key);
  }

  // merge 16 sorted lists x 10 per row -> top-16 window (MVK aliases CT0: safe,
  // CT0 last read during stripe-7 iteration, before its end barrier)
  u32* MVK = (u32*)(smem + KLCT0);                 // 16*32*10*4 = 20,480
  {
    const int r = t & 31, sub = t >> 5;
    #pragma unroll
    for (int j = 0; j < 10; ++j) MVK[(sub*32 + r)*10 + j] = key[j];
  }
  __syncthreads();
  if (t < 32){
    int head[16];
    #pragma unroll
    for (int q = 0; q < 16; ++q) head[q] = 9;
    const size_t ob = ((size_t)b*N_ + n0 + t) * 16;
    for (int s = 0; s < 16; ++s){
      u32 best = 0u; int bq = 0;
      #pragma unroll
      for (int q = 0; q < 16; ++q){
        int hh = head[q];
        u32 v = (hh >= 0) ? MVK[(q*32 + t)*10 + hh] : 0u;
        if (v > best){ best = v; bq = q; }
      }
      cand[ob + s] = (u16)(best & 2047u);
      #pragma unroll
      for (int q = 0; q < 16; ++q) head[q] -= (q == bq) ? 1 : 0;
    }
  }
}

// ---------------- K1b: f64 refine + fused counting, XCD-pinned, staged MLP ----------------
// R10/R11 postmortem: with no min-waves clause the backend targets max occupancy,
// minimizes VGPR (36), and SINKS the 24 gathers to their uses -> 12 serial latency
// rounds. (256,3) relaxes the target (cap ~168) so the staged an[]/am[] loads stay
// hoisted: 24 loads in flight, then pure f64 math (4 chains, validated in R10).
__global__ __launch_bounds__(256, 3) void refine_kernel(const float* __restrict__ xT,
                                                        const u16* __restrict__ cand,
                                                        const double* __restrict__ xxd,
                                                        int* __restrict__ idxout,
                                                        int* __restrict__ cnt){
  const int wv = threadIdx.x >> 6, ln = threadIdx.x & 63;
  const int b = blockIdx.x & 7;                    // XCD-pinned batch
  const int n = (blockIdx.x >> 3) * 4 + wv;        // 0..2047
  const int g = b * N_ + n;
  const int c = ln >> 2, part = ln & 3;
  const int m = (int)cand[(size_t)g*16 + c] & 2047;
  const float4* pn = (const float4*)(xT + ((size_t)b*N_ + n)*192 + part*48);
  const float4* pm = (const float4*)(xT + ((size_t)b*N_ + m)*192 + part*48);
  float4 an[12], am[12];
  #pragma unroll
  for (int j = 0; j < 12; ++j) an[j] = pn[j];
  #pragma unroll
  for (int j = 0; j < 12; ++j) am[j] = pm[j];
  double s0 = 0.0, s1 = 0.0, s2 = 0.0, s3 = 0.0;
  #pragma unroll
  for (int j = 0; j < 12; j += 4){
    s0 = fma((double)an[j+0].x, (double)am[j+0].x, s0);
    s0 = fma((double)an[j+0].y, (double)am[j+0].y, s0);
    s0 = fma((double)an[j+0].z, (double)am[j+0].z, s0);
    s0 = fma((double)an[j+0].w, (double)am[j+0].w, s0);
    s1 = fma((double)an[j+1].x, (double)am[j+1].x, s1);
    s1 = fma((double)an[j+1].y, (double)am[j+1].y, s1);
    s1 = fma((double)an[j+1].z, (double)am[j+1].z, s1);
    s1 = fma((double)an[j+1].w, (double)am[j+1].w, s1);
    s2 = fma((double)an[j+2].x, (double)am[j+2].x, s2);
    s2 = fma((double)an[j+2].y, (double)am[j+2].y, s2);
    s2 = fma((double)an[j+2].z, (double)am[j+2].z, s2);
    s2 = fma((double)an[j+2].w, (double)am[j+2].w, s2);
    s3 = fma((double)an[j+3].x, (double)am[j+3].x, s3);
    s3 = fma((double)an[j+3].y, (double)am[j+3].y, s3);
    s3 = fma((double)an[j+3].z, (double)am[j+3].z, s3);
    s3 = fma((double)an[j+3].w, (double)am[j+3].w, s3);
  }
  double s = (s0 + s1) + (s2 + s3);
  s += __shfl_down(s, 2, 64);
  s += __shfl_down(s, 1, 64);                      // part==0 lanes hold full dot
  double v = 2.0*s - xxd[b*N_ + n] - xxd[b*N_ + m];
  int rank = 0;
  #pragma unroll
  for (int q = 0; q < 16; ++q){
    double vq = __shfl(v, q*4, 64);
    int    mq = __shfl(m, q*4, 64);
    bool beat = (vq > v) || ((vq == v) && (mq < m));
    rank += beat ? 1 : 0;
  }
  if (part == 0 && rank < KNb){
    idxout[(size_t)g*KNb + rank] = m;
    atomicAdd(&cnt[b*N_ + m], 1);                  // fused count (same increment set)
  }
}

// ---------------- K2: P0/D0 from xT, 16-pt tiles, natural VGPR ----------------
// Spill ledger: any VGPR cap <=128 spills this body (~150 natural). Uncapped: clean.
__global__ __launch_bounds__(256) void project_kernel(const float* __restrict__ xT,
                                                      const float* __restrict__ Wf,
                                                      const float* __restrict__ Wd,
                                                      h4* __restrict__ P0h,
                                                      h4* __restrict__ D0h){
  __shared__ float A[16 * 192];                    // 12 KB, [m][e]
  const int b = blockIdx.x, m0 = blockIdx.y * 16, t = threadIdx.x;
  const int c = t & 63, mg = t >> 6;               // 4 groups of 4 points

  float wf[64], wd[64];
  #pragma unroll
  for (int q = 0; q < 16; ++q){
    float4 uf = *(const float4*)(Wf + c*64 + q*4);
    wf[q*4+0]=uf.x; wf[q*4+1]=uf.y; wf[q*4+2]=uf.z; wf[q*4+3]=uf.w;
    float4 ud = *(const float4*)(Wd + c*64 + q*4);
    wd[q*4+0]=ud.x; wd[q*4+1]=ud.y; wd[q*4+2]=ud.z; wd[q*4+3]=ud.w;
  }
  {
    const float4* src = (const float4*)(xT + ((size_t)b*N_ + m0)*192);
    float4* dst = (float4*)A;
    #pragma unroll
    for (int j = 0; j < 3; ++j) dst[t + 256*j] = src[t + 256*j];
  }
  __syncthreads();

  for (int mi = 0; mi < 4; ++mi){
    int m = mg*4 + mi;
    const float4* row = (const float4*)(A + m*192);
    float p[3] = {0.f,0.f,0.f}, qv[3] = {0.f,0.f,0.f};
    #pragma unroll
    for (int v4 = 0; v4 < 48; ++v4){
      float4 f = row[v4];
      const int e = v4*4;
      p [(e+0)%3] = fmaf(wf[(e+0)/3], f.x, p [(e+0)%3]);
      qv[(e+0)%3] = fmaf(wd[(e+0)/3], f.x, qv[(e+0)%3]);
      p [(e+1)%3] = fmaf(wf[(e+1)/3], f.y, p [(e+1)%3]);
      qv[(e+1)%3] = fmaf(wd[(e+1)/3], f.y, qv[(e+1)%3]);
      p [(e+2)%3] = fmaf(wf[(e+2)/3], f.z, p [(e+2)%3]);
      qv[(e+2)%3] = fmaf(wd[(e+2)/3], f.z, qv[(e+2)%3]);
      p [(e+3)%3] = fmaf(wf[(e+3)/3], f.w, p [(e+3)%3]);
      qv[(e+3)%3] = fmaf(wd[(e+3)/3], f.w, qv[(e+3)%3]);
    }
    float nrm = sqrtf(p[0]*p[0] + p[1]*p[1] + p[2]*p[2]);
    float dsq = qv[0]*qv[0] + qv[1]*qv[1] + qv[2]*qv[2];
    size_t base = ((size_t)b*N_ + m0 + m)*64 + c;
    h4 vp; vp.x = (f16)p[0];  vp.y = (f16)p[1];  vp.z = (f16)p[2];  vp.w = (f16)nrm;
    h4 vd; vd.x = (f16)qv[0]; vd.y = (f16)qv[1]; vd.z = (f16)qv[2]; vd.w = (f16)dsq;
    P0h[base] = vp;
    D0h[base] = vd;
  }
}

// ---------------- K3: per-channel weighted sum / sumsq of norms ----------------
__global__ __launch_bounds__(256) void stats_kernel(const h4* __restrict__ P0h,
                                                    const int* __restrict__ cnt,
                                                    float* __restrict__ gs){
  const int b = blockIdx.x >> 6;
  const int chunk = blockIdx.x & 63;
  const int w = threadIdx.x >> 6, c = threadIdx.x & 63;
  float s = 0.f, s2 = 0.f;
  const int mbase = chunk*32 + w*8;
  for (int i = 0; i < 8; ++i){
    int m = mbase + i;
    float wt = (float)cnt[b*N_ + m];
    float nv = (float)P0h[((size_t)b*N_ + m)*64 + c].w;
    s  = fmaf(wt, nv, s);
    s2 = fmaf(wt*nv, nv, s2);
  }
  __shared__ float red[8][64];
  red[w][c] = s; red[4+w][c] = s2;
  __syncthreads();
  if (w == 0) atomicAdd(&gs[c],    red[0][c]+red[1][c]+red[2][c]+red[3][c]);
  if (w == 1) atomicAdd(&gs[64+c], red[4][c]+red[5][c]+red[6][c]+red[7][c]);
}

// ---------------- K4: gather + BN + nonlinearity + mean over K ----------------
__global__ __launch_bounds__(512) void out_kernel(const h4* __restrict__ P0h, const h4* __restrict__ D0h,
                                                  const int* __restrict__ idxin, const float* __restrict__ gs,
                                                  const float* __restrict__ gamma, const float* __restrict__ beta,
                                                  float* __restrict__ outp){
  __shared__ float res[16 * 193];                  // 12,352 B
  const int b  = blockIdx.x;
  const int n0 = blockIdx.y * 16;
  const int t = threadIdx.x, w = t >> 6, c = t & 63;
  const float Ninv = 1.f / (float)(B_*N_*KNb);
  float mean = gs[c] * Ninv;
  float var  = gs[64+c] * Ninv - mean*mean;
  float istd = rsqrtf(var + 1e-5f);
  float sa = istd * gamma[c];
  float be = beta[c];
  const float kinv = 1.f/11.f;
  for (int i = 0; i < 2; ++i){
    int row = w*2 + i;
    int n = n0 + row;
    const int* ip = idxin + ((size_t)b*N_ + n)*KNb;
    float a0=0, a1=0, a2=0;
    #pragma unroll
    for (int k = 0; k < KNb; ++k){
      int m = ip[k] & 2047;
      size_t base = ((size_t)b*N_ + m)*64 + c;
      h4 P  = P0h[base];
      h4 Dv = D0h[base];
      float pw = (float)P.w;
      float nb = (pw - mean)*sa + be;
      float sc = nb / pw;
      float p0 = (float)P.x*sc, p1 = (float)P.y*sc, p2 = (float)P.z*sc;
      float d0 = (float)Dv.x, d1 = (float)Dv.y, d2 = (float)Dv.z;
      float dot = p0*d0 + p1*d1 + p2*d2;
      float f = (dot >= 0.f) ? 0.f : dot / ((float)Dv.w + 1e-6f);
      a0 += p0 - f*d0; a1 += p1 - f*d1; a2 += p2 - f*d2;
    }
    res[row*193 + 3*c + 0] = a0*kinv;
    res[row*193 + 3*c + 1] = a1*kinv;
    res[row*193 + 3*c + 2] = a2*kinv;
  }
  __syncthreads();
  {
    int p = t;                                     // 768 float4 stores: 512 + 256
    #pragma unroll
    for (int j = 0; j < 2; ++j){
      if (p < 768){
        int cdim = p >> 2, nq = p & 3;
        float4 v = { res[(nq*4 + 0)*193 + cdim], res[(nq*4 + 1)*193 + cdim],
                     res[(nq*4 + 2)*193 + cdim], res[(nq*4 + 3)*193 + cdim] };
        *(float4*)(outp + ((size_t)b*192 + cdim)*N_ + n0 + nq*4) = v;
      }
      p += 512;
    }
  }
}

extern "C" void kernel_launch(void* const* d_in, const int* in_sizes, int n_in,
                              void* d_out, int out_size, void* d_ws, size_t ws_size,
                              hipStream_t stream){
  const float* x     = (const float*)d_in[0];
  const float* Wf    = (const float*)d_in[1];
  const float* Wd    = (const float*)d_in[2];
  const float* gamma = (const float*)d_in[3];
  const float* beta  = (const float*)d_in[4];
  float* outp = (float*)d_out;

  char* ws = (char*)d_ws;
  int*    idx  = (int*)   (ws);                 // 720,896
  int*    cnt  = (int*)   (ws + 720896);        // 65,536
  float*  gs   = (float*) (ws + 786432);        // 512
  h4*     P0h  = (h4*)    (ws + 1048576);       // 8,388,608
  h4*     D0h  = (h4*)    (ws + 9437184);       // 8,388,608 (ends 17,825,792)
  short*  Xs   = (short*) (ws + 1048576);       //   alias (6,291,456), consumed pre-project
  double* xxd  = (double*)(ws + 13631488);      //   alias (lives in D0h region pre-project)
  u16*    cand = (u16*)   (ws + 13762560);      //   alias
  float*  xT   = (float*) (ws + 17825792);      // 12,582,912 (ends 30,408,704)

  hipMemsetAsync(cnt, 0, 66048, stream);        // zero cnt + gs (contiguous)
  split_kernel  <<<dim3(64, 8),  256, 0, stream>>>(x, Xs, xT, xxd);
  knn_kernel    <<<dim3(8, 64),  512, 0, stream>>>(Xs, xxd, cand);
  refine_kernel <<<4096,         256, 0, stream>>>(xT, cand, xxd, idx, cnt);
  project_kernel<<<dim3(8, 128), 256, 0, stream>>>(xT, Wf, Wd, P0h, D0h);
  stats_kernel  <<<512,          256, 0, stream>>>(P0h, cnt, gs);
  out_kernel    <<<dim3(8, 128), 512, 0, stream>>>(P0h, D0h, idx, gs, gamma, beta, outp);
}

// Round 13
// 252.087 us; speedup vs baseline: 1.0252x; 1.0252x over previous
//
#include <hip/hip_runtime.h>
#include <stdint.h>

#define B_   8
#define D_   192      // Cin*3
#define N_   2048
#define KNb  11       // k+1

using u32 = uint32_t;
using u16 = unsigned short;
typedef _Float16 f16;
struct alignas(8) h4 { f16 x, y, z, w; };

typedef __attribute__((ext_vector_type(8)))  short short8;
typedef __attribute__((ext_vector_type(16))) float f32x16;

__device__ __forceinline__ u16 f2bf(float f){
  union{float f; u32 i;} x; x.f = f;
  u32 r = (x.i + 0x7fffu + ((x.i >> 16) & 1u)) >> 16;
  return (u16)r;
}
__device__ __forceinline__ u32 umax32(u32 a, u32 b){ return a > b ? a : b; }
__device__ __forceinline__ u32 umin32(u32 a, u32 b){ return a < b ? a : b; }
// median-of-3 unsigned: single VOP3 op on gfx9+; compiler won't pattern-match
// the u32 min(max) pair, so emit explicitly.
__device__ __forceinline__ u32 med3_u32(u32 a, u32 b, u32 c){
  u32 d;
  asm("v_med3_u32 %0, %1, %2, %3" : "=v"(d) : "v"(a), "v"(b), "v"(c));
  return d;
}

// branchless sorted-insert of 16 packed keys into ascending key[10].
// Insertion step key[s]=min(key[s+1],max(kk,key[s])) == median(kk,key[s],key[s+1])
// (kk below both -> key[s]; between -> kk; above both -> key[s+1]) => 1 op/step.
__device__ __forceinline__ void sel16(const u32* __restrict__ ctp, u32* key){
  #pragma unroll
  for (int q = 0; q < 4; ++q){
    uint4 kv = *(const uint4*)(ctp + 4*q);
    u32 ks[4] = {kv.x, kv.y, kv.z, kv.w};
    #pragma unroll
    for (int j = 0; j < 4; ++j){
      u32 kk = ks[j];
      #pragma unroll
      for (int s = 0; s < 9; ++s) key[s] = med3_u32(kk, key[s], key[s+1]);
      key[9] = umax32(kk, key[9]);
    }
  }
}

// ---------------- K0: bf16 fragment-page emit + fp32 transpose + f64 xx ----------------
// 32-pt tiles (24KB LDS) -> grid (64,8)=512 blocks = 2 blocks/CU.
// Xs layout: page P=(b*64+tile)*12+chunk, [lane][8 bf16] fragment order.
__global__ __launch_bounds__(256) void split_kernel(const float* __restrict__ x,
                                                    short* __restrict__ Xs,
                                                    float* __restrict__ xT,
                                                    double* __restrict__ xxd){
  __shared__ float A[D_ * 32];                       // 24 KB, [d][m]
  const int b = blockIdx.y, tile = blockIdx.x, m0 = tile * 32, t = threadIdx.x;
  const size_t xb = (size_t)b * D_ * N_;
  #pragma unroll
  for (int q = 0; q < 24; ++q){
    int p = t + 256*q;
    int d = p >> 5, i = p & 31;
    A[d*32 + i] = x[xb + (size_t)d*N_ + m0 + i];
  }
  __syncthreads();

  {
    const int l = t & 63, wv = t >> 6;
    const int lh = l >> 5, l31 = l & 31;
    #pragma unroll
    for (int j = 0; j < 3; ++j){
      int c = j*4 + wv;                  // chunk 0..11
      int dbase = c*16 + lh*8;
      union{ u16 s[8]; int4 v; } u;
      #pragma unroll
      for (int q = 0; q < 8; ++q) u.s[q] = f2bf(A[(dbase + q)*32 + l31]);
      size_t P = ((size_t)b*64 + tile)*12 + c;
      *(int4*)(Xs + P*512 + l*8) = u.v;
    }
  }
  {
    const int m = t & 31, seg = t >> 5;  // 8 segs of 24 d's
    float* trow = xT + ((size_t)b*N_ + m0 + m) * 192 + seg*24;
    #pragma unroll
    for (int j = 0; j < 6; ++j){
      float4 v = { A[(seg*24 + 4*j + 0)*32 + m], A[(seg*24 + 4*j + 1)*32 + m],
                   A[(seg*24 + 4*j + 2)*32 + m], A[(seg*24 + 4*j + 3)*32 + m] };
      *(float4*)(trow + 4*j) = v;
    }
  }
  if (t < 32){
    double s = 0.0;
    #pragma unroll 4
    for (int d = 0; d < D_; ++d){ double v = (double)A[d*32 + t]; s = fma(v, v, s); }
    xxd[b*N_ + m0 + t] = s;
  }
}

// ---------------- K1: MFMA kNN, full-stripe register prefetch ----------------
// R12 accounting: wall 120k cy/CU; VALU issue ~53k (44%) with sel16 ~60% of it.
// R13: med3_u32 ladder (19->10 ops/insert) cuts sel16 ~2x.
#define KLA   0         // 12,288 : A pages
#define KLCT0 12288     // u32[32*260] = 33,280 (buffer 0; aliased by merge keys)
#define KLCT1 45568     // u32[32*260] = 33,280 (buffer 1)
#define KLSZ  78848
__global__ __launch_bounds__(512, 4) void knn_kernel(const short* __restrict__ Xs,
                                                     const double* __restrict__ xxd,
                                                     u16* __restrict__ cand){
  __shared__ __align__(16) char smem[KLSZ];

  const int b = blockIdx.x, n0 = blockIdx.y * 32;
  const int t = threadIdx.x, lane = t & 63, w = t >> 6;
  const int l31 = lane & 31, lh = lane >> 5;
  const int mcol = w*32 + l31;

  // stage A (12 pages = query tile n0>>5)
  {
    const short* Ap = Xs + (((size_t)b*64 + (n0 >> 5)) * 12) * 512;
    int4 v = *(const int4*)(Ap + (size_t)t*8);
    *(int4*)(smem + KLA + t*16) = v;
    if (t < 256){
      int p = t + 512;
      int4 v2 = *(const int4*)(Ap + (size_t)p*8);
      *(int4*)(smem + KLA + p*16) = v2;
    }
  }
  // query-row norms in registers (constant over stripes)
  float xxn[16];
  #pragma unroll
  for (int reg = 0; reg < 16; ++reg){
    int r = (reg & 3) + 8*(reg >> 2) + 4*lh;
    xxn[reg] = (float)xxd[b*N_ + n0 + r];
  }
  __syncthreads();                                 // A staged

  u32 key[10];
  #pragma unroll
  for (int j = 0; j < 10; ++j) key[j] = 0u;

  for (int st = 0; st < 8; ++st){
    const int m0 = st * 256;
    // wave w consumes neighbor tile st*8+w: issue ALL 12 page loads up front
    const short* Bp = Xs + (((size_t)b*64 + st*8 + w) * 12) * 512 + lane*8;
    short8 pg[12];
    #pragma unroll
    for (int j = 0; j < 12; ++j) pg[j] = *(const short8*)(Bp + j*512);
    float xxs = (float)xxd[b*N_ + m0 + mcol];

    // selection of previous stripe overlaps the load flight above
    if (st > 0){
      const u32* ctp = (const u32*)(smem + ((st & 1) ? KLCT0 : KLCT1))
                       + (t & 31)*260 + (t >> 5)*16;
      sel16(ctp, key);
    }

    f32x16 acc = (f32x16)0.0f;
    #pragma unroll
    for (int kc = 0; kc < 6; ++kc){
      short8 a0 = *(const short8*)(smem + KLA + (kc*2+0)*1024 + lane*16);
      short8 a1 = *(const short8*)(smem + KLA + (kc*2+1)*1024 + lane*16);
      acc = __builtin_amdgcn_mfma_f32_32x32x16_bf16(a0, pg[kc*2+0], acc, 0, 0, 0);
      acc = __builtin_amdgcn_mfma_f32_32x32x16_bf16(a1, pg[kc*2+1], acc, 0, 0, 0);
    }

    // pack keys in registers, write to this stripe's buffer
    {
      u32* ctw = (u32*)(smem + ((st & 1) ? KLCT1 : KLCT0));
      const u32 midx = (u32)(m0 + mcol);
      #pragma unroll
      for (int reg = 0; reg < 16; ++reg){
        float v = fmaf(2.f, acc[reg], -(xxs + xxn[reg]));
        u32 bb = __float_as_uint(v);
        u32 kk = ((bb ^ (u32)(((int)bb >> 31) | 0x80000000)) & 0xFFFFF800u) | midx;
        int r = (reg & 3) + 8*(reg >> 2) + 4*lh;
        ctw[r*260 + mcol] = kk;
      }
    }
    __syncthreads();                               // one barrier per stripe
  }
  // final stripe's selection (stripe 7 wrote KLCT1)
  {
    const u32* ctp = (const u32*)(smem + KLCT1) + (t & 31)*260 + (t >> 5)*16;
    sel16(ctp, key);
  }

  // merge 16 sorted lists x 10 per row -> top-16 window (MVK aliases CT0: safe,
  // CT0 last read during stripe-7 iteration, before its end barrier)
  u32* MVK = (u32*)(smem + KLCT0);                 // 16*32*10*4 = 20,480
  {
    const int r = t & 31, sub = t >> 5;
    #pragma unroll
    for (int j = 0; j < 10; ++j) MVK[(sub*32 + r)*10 + j] = key[j];
  }
  __syncthreads();
  if (t < 32){
    int head[16];
    #pragma unroll
    for (int q = 0; q < 16; ++q) head[q] = 9;
    const size_t ob = ((size_t)b*N_ + n0 + t) * 16;
    for (int s = 0; s < 16; ++s){
      u32 best = 0u; int bq = 0;
      #pragma unroll
      for (int q = 0; q < 16; ++q){
        int hh = head[q];
        u32 v = (hh >= 0) ? MVK[(q*32 + t)*10 + hh] : 0u;
        if (v > best){ best = v; bq = q; }
      }
      cand[ob + s] = (u16)(best & 2047u);
      #pragma unroll
      for (int q = 0; q < 16; ++q) head[q] -= (q == bq) ? 1 : 0;
    }
  }
}

// ---------------- K1b: f64 refine + fused counting, XCD-pinned, staged MLP ----------------
__global__ __launch_bounds__(256, 3) void refine_kernel(const float* __restrict__ xT,
                                                        const u16* __restrict__ cand,
                                                        const double* __restrict__ xxd,
                                                        int* __restrict__ idxout,
                                                        int* __restrict__ cnt){
  const int wv = threadIdx.x >> 6, ln = threadIdx.x & 63;
  const int b = blockIdx.x & 7;                    // XCD-pinned batch
  const int n = (blockIdx.x >> 3) * 4 + wv;        // 0..2047
  const int g = b * N_ + n;
  const int c = ln >> 2, part = ln & 3;
  const int m = (int)cand[(size_t)g*16 + c] & 2047;
  const float4* pn = (const float4*)(xT + ((size_t)b*N_ + n)*192 + part*48);
  const float4* pm = (const float4*)(xT + ((size_t)b*N_ + m)*192 + part*48);
  float4 an[12], am[12];
  #pragma unroll
  for (int j = 0; j < 12; ++j) an[j] = pn[j];
  #pragma unroll
  for (int j = 0; j < 12; ++j) am[j] = pm[j];
  double s0 = 0.0, s1 = 0.0, s2 = 0.0, s3 = 0.0;
  #pragma unroll
  for (int j = 0; j < 12; j += 4){
    s0 = fma((double)an[j+0].x, (double)am[j+0].x, s0);
    s0 = fma((double)an[j+0].y, (double)am[j+0].y, s0);
    s0 = fma((double)an[j+0].z, (double)am[j+0].z, s0);
    s0 = fma((double)an[j+0].w, (double)am[j+0].w, s0);
    s1 = fma((double)an[j+1].x, (double)am[j+1].x, s1);
    s1 = fma((double)an[j+1].y, (double)am[j+1].y, s1);
    s1 = fma((double)an[j+1].z, (double)am[j+1].z, s1);
    s1 = fma((double)an[j+1].w, (double)am[j+1].w, s1);
    s2 = fma((double)an[j+2].x, (double)am[j+2].x, s2);
    s2 = fma((double)an[j+2].y, (double)am[j+2].y, s2);
    s2 = fma((double)an[j+2].z, (double)am[j+2].z, s2);
    s2 = fma((double)an[j+2].w, (double)am[j+2].w, s2);
    s3 = fma((double)an[j+3].x, (double)am[j+3].x, s3);
    s3 = fma((double)an[j+3].y, (double)am[j+3].y, s3);
    s3 = fma((double)an[j+3].z, (double)am[j+3].z, s3);
    s3 = fma((double)an[j+3].w, (double)am[j+3].w, s3);
  }
  double s = (s0 + s1) + (s2 + s3);
  s += __shfl_down(s, 2, 64);
  s += __shfl_down(s, 1, 64);                      // part==0 lanes hold full dot
  double v = 2.0*s - xxd[b*N_ + n] - xxd[b*N_ + m];
  int rank = 0;
  #pragma unroll
  for (int q = 0; q < 16; ++q){
    double vq = __shfl(v, q*4, 64);
    int    mq = __shfl(m, q*4, 64);
    bool beat = (vq > v) || ((vq == v) && (mq < m));
    rank += beat ? 1 : 0;
  }
  if (part == 0 && rank < KNb){
    idxout[(size_t)g*KNb + rank] = m;
    atomicAdd(&cnt[b*N_ + m], 1);                  // fused count (same increment set)
  }
}

// ---------------- K2: P0/D0 from xT, 16-pt tiles, natural VGPR ----------------
// Spill ledger: any VGPR cap <=128 spills this body (~150 natural). Uncapped: clean.
__global__ __launch_bounds__(256) void project_kernel(const float* __restrict__ xT,
                                                      const float* __restrict__ Wf,
                                                      const float* __restrict__ Wd,
                                                      h4* __restrict__ P0h,
                                                      h4* __restrict__ D0h){
  __shared__ float A[16 * 192];                    // 12 KB, [m][e]
  const int b = blockIdx.x, m0 = blockIdx.y * 16, t = threadIdx.x;
  const int c = t & 63, mg = t >> 6;               // 4 groups of 4 points

  float wf[64], wd[64];
  #pragma unroll
  for (int q = 0; q < 16; ++q){
    float4 uf = *(const float4*)(Wf + c*64 + q*4);
    wf[q*4+0]=uf.x; wf[q*4+1]=uf.y; wf[q*4+2]=uf.z; wf[q*4+3]=uf.w;
    float4 ud = *(const float4*)(Wd + c*64 + q*4);
    wd[q*4+0]=ud.x; wd[q*4+1]=ud.y; wd[q*4+2]=ud.z; wd[q*4+3]=ud.w;
  }
  {
    const float4* src = (const float4*)(xT + ((size_t)b*N_ + m0)*192);
    float4* dst = (float4*)A;
    #pragma unroll
    for (int j = 0; j < 3; ++j) dst[t + 256*j] = src[t + 256*j];
  }
  __syncthreads();

  for (int mi = 0; mi < 4; ++mi){
    int m = mg*4 + mi;
    const float4* row = (const float4*)(A + m*192);
    float p[3] = {0.f,0.f,0.f}, qv[3] = {0.f,0.f,0.f};
    #pragma unroll
    for (int v4 = 0; v4 < 48; ++v4){
      float4 f = row[v4];
      const int e = v4*4;
      p [(e+0)%3] = fmaf(wf[(e+0)/3], f.x, p [(e+0)%3]);
      qv[(e+0)%3] = fmaf(wd[(e+0)/3], f.x, qv[(e+0)%3]);
      p [(e+1)%3] = fmaf(wf[(e+1)/3], f.y, p [(e+1)%3]);
      qv[(e+1)%3] = fmaf(wd[(e+1)/3], f.y, qv[(e+1)%3]);
      p [(e+2)%3] = fmaf(wf[(e+2)/3], f.z, p [(e+2)%3]);
      qv[(e+2)%3] = fmaf(wd[(e+2)/3], f.z, qv[(e+2)%3]);
      p [(e+3)%3] = fmaf(wf[(e+3)/3], f.w, p [(e+3)%3]);
      qv[(e+3)%3] = fmaf(wd[(e+3)/3], f.w, qv[(e+3)%3]);
    }
    float nrm = sqrtf(p[0]*p[0] + p[1]*p[1] + p[2]*p[2]);
    float dsq = qv[0]*qv[0] + qv[1]*qv[1] + qv[2]*qv[2];
    size_t base = ((size_t)b*N_ + m0 + m)*64 + c;
    h4 vp; vp.x = (f16)p[0];  vp.y = (f16)p[1];  vp.z = (f16)p[2];  vp.w = (f16)nrm;
    h4 vd; vd.x = (f16)qv[0]; vd.y = (f16)qv[1]; vd.z = (f16)qv[2]; vd.w = (f16)dsq;
    P0h[base] = vp;
    D0h[base] = vd;
  }
}

// ---------------- K3: per-channel weighted sum / sumsq of norms ----------------
__global__ __launch_bounds__(256) void stats_kernel(const h4* __restrict__ P0h,
                                                    const int* __restrict__ cnt,
                                                    float* __restrict__ gs){
  const int b = blockIdx.x >> 6;
  const int chunk = blockIdx.x & 63;
  const int w = threadIdx.x >> 6, c = threadIdx.x & 63;
  float s = 0.f, s2 = 0.f;
  const int mbase = chunk*32 + w*8;
  for (int i = 0; i < 8; ++i){
    int m = mbase + i;
    float wt = (float)cnt[b*N_ + m];
    float nv = (float)P0h[((size_t)b*N_ + m)*64 + c].w;
    s  = fmaf(wt, nv, s);
    s2 = fmaf(wt*nv, nv, s2);
  }
  __shared__ float red[8][64];
  red[w][c] = s; red[4+w][c] = s2;
  __syncthreads();
  if (w == 0) atomicAdd(&gs[c],    red[0][c]+red[1][c]+red[2][c]+red[3][c]);
  if (w == 1) atomicAdd(&gs[64+c], red[4][c]+red[5][c]+red[6][c]+red[7][c]);
}

// ---------------- K4: gather + BN + nonlinearity + mean over K ----------------
__global__ __launch_bounds__(512) void out_kernel(const h4* __restrict__ P0h, const h4* __restrict__ D0h,
                                                  const int* __restrict__ idxin, const float* __restrict__ gs,
                                                  const float* __restrict__ gamma, const float* __restrict__ beta,
                                                  float* __restrict__ outp){
  __shared__ float res[16 * 193];                  // 12,352 B
  const int b  = blockIdx.x;
  const int n0 = blockIdx.y * 16;
  const int t = threadIdx.x, w = t >> 6, c = t & 63;
  const float Ninv = 1.f / (float)(B_*N_*KNb);
  float mean = gs[c] * Ninv;
  float var  = gs[64+c] * Ninv - mean*mean;
  float istd = rsqrtf(var + 1e-5f);
  float sa = istd * gamma[c];
  float be = beta[c];
  const float kinv = 1.f/11.f;
  for (int i = 0; i < 2; ++i){
    int row = w*2 + i;
    int n = n0 + row;
    const int* ip = idxin + ((size_t)b*N_ + n)*KNb;
    float a0=0, a1=0, a2=0;
    #pragma unroll
    for (int k = 0; k < KNb; ++k){
      int m = ip[k] & 2047;
      size_t base = ((size_t)b*N_ + m)*64 + c;
      h4 P  = P0h[base];
      h4 Dv = D0h[base];
      float pw = (float)P.w;
      float nb = (pw - mean)*sa + be;
      float sc = nb / pw;
      float p0 = (float)P.x*sc, p1 = (float)P.y*sc, p2 = (float)P.z*sc;
      float d0 = (float)Dv.x, d1 = (float)Dv.y, d2 = (float)Dv.z;
      float dot = p0*d0 + p1*d1 + p2*d2;
      float f = (dot >= 0.f) ? 0.f : dot / ((float)Dv.w + 1e-6f);
      a0 += p0 - f*d0; a1 += p1 - f*d1; a2 += p2 - f*d2;
    }
    res[row*193 + 3*c + 0] = a0*kinv;
    res[row*193 + 3*c + 1] = a1*kinv;
    res[row*193 + 3*c + 2] = a2*kinv;
  }
  __syncthreads();
  {
    int p = t;                                     // 768 float4 stores: 512 + 256
    #pragma unroll
    for (int j = 0; j < 2; ++j){
      if (p < 768){
        int cdim = p >> 2, nq = p & 3;
        float4 v = { res[(nq*4 + 0)*193 + cdim], res[(nq*4 + 1)*193 + cdim],
                     res[(nq*4 + 2)*193 + cdim], res[(nq*4 + 3)*193 + cdim] };
        *(float4*)(outp + ((size_t)b*192 + cdim)*N_ + n0 + nq*4) = v;
      }
      p += 512;
    }
  }
}

extern "C" void kernel_launch(void* const* d_in, const int* in_sizes, int n_in,
                              void* d_out, int out_size, void* d_ws, size_t ws_size,
                              hipStream_t stream){
  const float* x     = (const float*)d_in[0];
  const float* Wf    = (const float*)d_in[1];
  const float* Wd    = (const float*)d_in[2];
  const float* gamma = (const float*)d_in[3];
  const float* beta  = (const float*)d_in[4];
  float* outp = (float*)d_out;

  char* ws = (char*)d_ws;
  int*    idx  = (int*)   (ws);                 // 720,896
  int*    cnt  = (int*)   (ws + 720896);        // 65,536
  float*  gs   = (float*) (ws + 786432);        // 512
  h4*     P0h  = (h4*)    (ws + 1048576);       // 8,388,608
  h4*     D0h  = (h4*)    (ws + 9437184);       // 8,388,608 (ends 17,825,792)
  short*  Xs   = (short*) (ws + 1048576);       //   alias (6,291,456), consumed pre-project
  double* xxd  = (double*)(ws + 13631488);      //   alias (lives in D0h region pre-project)
  u16*    cand = (u16*)   (ws + 13762560);      //   alias
  float*  xT   = (float*) (ws + 17825792);      // 12,582,912 (ends 30,408,704)

  hipMemsetAsync(cnt, 0, 66048, stream);        // zero cnt + gs (contiguous)
  split_kernel  <<<dim3(64, 8),  256, 0, stream>>>(x, Xs, xT, xxd);
  knn_kernel    <<<dim3(8, 64),  512, 0, stream>>>(Xs, xxd, cand);
  refine_kernel <<<4096,         256, 0, stream>>>(xT, cand, xxd, idx, cnt);
  project_kernel<<<dim3(8, 128), 256, 0, stream>>>(xT, Wf, Wd, P0h, D0h);
  stats_kernel  <<<512,          256, 0, stream>>>(P0h, cnt, gs);
  out_kernel    <<<dim3(8, 128), 512, 0, stream>>>(P0h, D0h, idx, gs, gamma, beta, outp);
}

// Round 14
// 233.003 us; speedup vs baseline: 1.1092x; 1.0819x over previous
//
#include <hip/hip_runtime.h>
#include <stdint.h>

#define B_   8
#define D_   192      // Cin*3
#define N_   2048
#define KNb  11       // k+1

using u32 = uint32_t;
using u16 = unsigned short;
typedef _Float16 f16;
struct alignas(8) h4 { f16 x, y, z, w; };

typedef __attribute__((ext_vector_type(8)))  short short8;
typedef __attribute__((ext_vector_type(16))) float f32x16;

__device__ __forceinline__ u16 f2bf(float f){
  union{float f; u32 i;} x; x.f = f;
  u32 r = (x.i + 0x7fffu + ((x.i >> 16) & 1u)) >> 16;
  return (u16)r;
}
__device__ __forceinline__ u32 umax32(u32 a, u32 b){ return a > b ? a : b; }
__device__ __forceinline__ u32 umin32(u32 a, u32 b){ return a < b ? a : b; }
// median-of-3 unsigned: single VOP3 op on gfx9+; compiler won't pattern-match
// the u32 min(max) pair, so emit explicitly.
__device__ __forceinline__ u32 med3_u32(u32 a, u32 b, u32 c){
  u32 d;
  asm("v_med3_u32 %0, %1, %2, %3" : "=v"(d) : "v"(a), "v"(b), "v"(c));
  return d;
}

// branchless sorted-insert of 16 packed keys into ascending key[10].
__device__ __forceinline__ void sel16(const u32* __restrict__ ctp, u32* key){
  #pragma unroll
  for (int q = 0; q < 4; ++q){
    uint4 kv = *(const uint4*)(ctp + 4*q);
    u32 ks[4] = {kv.x, kv.y, kv.z, kv.w};
    #pragma unroll
    for (int j = 0; j < 4; ++j){
      u32 kk = ks[j];
      #pragma unroll
      for (int s = 0; s < 9; ++s) key[s] = med3_u32(kk, key[s], key[s+1]);
      key[9] = umax32(kk, key[9]);
    }
  }
}

// ---------------- K0: bf16 fragment-page emit + fp32 transpose + f64 xx ----------------
__global__ __launch_bounds__(256) void split_kernel(const float* __restrict__ x,
                                                    short* __restrict__ Xs,
                                                    float* __restrict__ xT,
                                                    double* __restrict__ xxd){
  __shared__ float A[D_ * 32];                       // 24 KB, [d][m]
  const int b = blockIdx.y, tile = blockIdx.x, m0 = tile * 32, t = threadIdx.x;
  const size_t xb = (size_t)b * D_ * N_;
  #pragma unroll
  for (int q = 0; q < 24; ++q){
    int p = t + 256*q;
    int d = p >> 5, i = p & 31;
    A[d*32 + i] = x[xb + (size_t)d*N_ + m0 + i];
  }
  __syncthreads();

  {
    const int l = t & 63, wv = t >> 6;
    const int lh = l >> 5, l31 = l & 31;
    #pragma unroll
    for (int j = 0; j < 3; ++j){
      int c = j*4 + wv;                  // chunk 0..11
      int dbase = c*16 + lh*8;
      union{ u16 s[8]; int4 v; } u;
      #pragma unroll
      for (int q = 0; q < 8; ++q) u.s[q] = f2bf(A[(dbase + q)*32 + l31]);
      size_t P = ((size_t)b*64 + tile)*12 + c;
      *(int4*)(Xs + P*512 + l*8) = u.v;
    }
  }
  {
    const int m = t & 31, seg = t >> 5;  // 8 segs of 24 d's
    float* trow = xT + ((size_t)b*N_ + m0 + m) * 192 + seg*24;
    #pragma unroll
    for (int j = 0; j < 6; ++j){
      float4 v = { A[(seg*24 + 4*j + 0)*32 + m], A[(seg*24 + 4*j + 1)*32 + m],
                   A[(seg*24 + 4*j + 2)*32 + m], A[(seg*24 + 4*j + 3)*32 + m] };
      *(float4*)(trow + 4*j) = v;
    }
  }
  if (t < 32){
    double s = 0.0;
    #pragma unroll 4
    for (int d = 0; d < D_; ++d){ double v = (double)A[d*32 + t]; s = fma(v, v, s); }
    xxd[b*N_ + m0 + t] = s;
  }
}

// ---------------- K1: MFMA kNN, full-stripe register prefetch + med3 select ----------------
#define KLA   0         // 12,288 : A pages
#define KLCT0 12288     // u32[32*260] = 33,280 (buffer 0; aliased by merge keys)
#define KLCT1 45568     // u32[32*260] = 33,280 (buffer 1)
#define KLSZ  78848
__global__ __launch_bounds__(512, 4) void knn_kernel(const short* __restrict__ Xs,
                                                     const double* __restrict__ xxd,
                                                     u16* __restrict__ cand){
  __shared__ __align__(16) char smem[KLSZ];

  const int b = blockIdx.x, n0 = blockIdx.y * 32;
  const int t = threadIdx.x, lane = t & 63, w = t >> 6;
  const int l31 = lane & 31, lh = lane >> 5;
  const int mcol = w*32 + l31;

  // stage A (12 pages = query tile n0>>5)
  {
    const short* Ap = Xs + (((size_t)b*64 + (n0 >> 5)) * 12) * 512;
    int4 v = *(const int4*)(Ap + (size_t)t*8);
    *(int4*)(smem + KLA + t*16) = v;
    if (t < 256){
      int p = t + 512;
      int4 v2 = *(const int4*)(Ap + (size_t)p*8);
      *(int4*)(smem + KLA + p*16) = v2;
    }
  }
  // query-row norms in registers (constant over stripes)
  float xxn[16];
  #pragma unroll
  for (int reg = 0; reg < 16; ++reg){
    int r = (reg & 3) + 8*(reg >> 2) + 4*lh;
    xxn[reg] = (float)xxd[b*N_ + n0 + r];
  }
  __syncthreads();                                 // A staged

  u32 key[10];
  #pragma unroll
  for (int j = 0; j < 10; ++j) key[j] = 0u;

  for (int st = 0; st < 8; ++st){
    const int m0 = st * 256;
    // wave w consumes neighbor tile st*8+w: issue ALL 12 page loads up front
    const short* Bp = Xs + (((size_t)b*64 + st*8 + w) * 12) * 512 + lane*8;
    short8 pg[12];
    #pragma unroll
    for (int j = 0; j < 12; ++j) pg[j] = *(const short8*)(Bp + j*512);
    float xxs = (float)xxd[b*N_ + m0 + mcol];

    // selection of previous stripe overlaps the load flight above
    if (st > 0){
      const u32* ctp = (const u32*)(smem + ((st & 1) ? KLCT0 : KLCT1))
                       + (t & 31)*260 + (t >> 5)*16;
      sel16(ctp, key);
    }

    f32x16 acc = (f32x16)0.0f;
    #pragma unroll
    for (int kc = 0; kc < 6; ++kc){
      short8 a0 = *(const short8*)(smem + KLA + (kc*2+0)*1024 + lane*16);
      short8 a1 = *(const short8*)(smem + KLA + (kc*2+1)*1024 + lane*16);
      acc = __builtin_amdgcn_mfma_f32_32x32x16_bf16(a0, pg[kc*2+0], acc, 0, 0, 0);
      acc = __builtin_amdgcn_mfma_f32_32x32x16_bf16(a1, pg[kc*2+1], acc, 0, 0, 0);
    }

    // pack keys in registers, write to this stripe's buffer
    {
      u32* ctw = (u32*)(smem + ((st & 1) ? KLCT1 : KLCT0));
      const u32 midx = (u32)(m0 + mcol);
      #pragma unroll
      for (int reg = 0; reg < 16; ++reg){
        float v = fmaf(2.f, acc[reg], -(xxs + xxn[reg]));
        u32 bb = __float_as_uint(v);
        u32 kk = ((bb ^ (u32)(((int)bb >> 31) | 0x80000000)) & 0xFFFFF800u) | midx;
        int r = (reg & 3) + 8*(reg >> 2) + 4*lh;
        ctw[r*260 + mcol] = kk;
      }
    }
    __syncthreads();                               // one barrier per stripe
  }
  // final stripe's selection (stripe 7 wrote KLCT1)
  {
    const u32* ctp = (const u32*)(smem + KLCT1) + (t & 31)*260 + (t >> 5)*16;
    sel16(ctp, key);
  }

  // merge 16 sorted lists x 10 per row -> top-16 window
  u32* MVK = (u32*)(smem + KLCT0);                 // 16*32*10*4 = 20,480
  {
    const int r = t & 31, sub = t >> 5;
    #pragma unroll
    for (int j = 0; j < 10; ++j) MVK[(sub*32 + r)*10 + j] = key[j];
  }
  __syncthreads();
  if (t < 32){
    int head[16];
    #pragma unroll
    for (int q = 0; q < 16; ++q) head[q] = 9;
    const size_t ob = ((size_t)b*N_ + n0 + t) * 16;
    for (int s = 0; s < 16; ++s){
      u32 best = 0u; int bq = 0;
      #pragma unroll
      for (int q = 0; q < 16; ++q){
        int hh = head[q];
        u32 v = (hh >= 0) ? MVK[(q*32 + t)*10 + hh] : 0u;
        if (v > best){ best = v; bq = q; }
      }
      cand[ob + s] = (u16)(best & 2047u);
      #pragma unroll
      for (int q = 0; q < 16; ++q) head[q] -= (q == bq) ? 1 : 0;
    }
  }
}

// ---------------- K1b: f64 refine + fused counting, XCD-pinned, staged MLP ----------------
__global__ __launch_bounds__(256, 3) void refine_kernel(const float* __restrict__ xT,
                                                        const u16* __restrict__ cand,
                                                        const double* __restrict__ xxd,
                                                        int* __restrict__ idxout,
                                                        int* __restrict__ cnt){
  const int wv = threadIdx.x >> 6, ln = threadIdx.x & 63;
  const int b = blockIdx.x & 7;                    // XCD-pinned batch
  const int n = (blockIdx.x >> 3) * 4 + wv;        // 0..2047
  const int g = b * N_ + n;
  const int c = ln >> 2, part = ln & 3;
  const int m = (int)cand[(size_t)g*16 + c] & 2047;
  const float4* pn = (const float4*)(xT + ((size_t)b*N_ + n)*192 + part*48);
  const float4* pm = (const float4*)(xT + ((size_t)b*N_ + m)*192 + part*48);
  float4 an[12], am[12];
  #pragma unroll
  for (int j = 0; j < 12; ++j) an[j] = pn[j];
  #pragma unroll
  for (int j = 0; j < 12; ++j) am[j] = pm[j];
  double s0 = 0.0, s1 = 0.0, s2 = 0.0, s3 = 0.0;
  #pragma unroll
  for (int j = 0; j < 12; j += 4){
    s0 = fma((double)an[j+0].x, (double)am[j+0].x, s0);
    s0 = fma((double)an[j+0].y, (double)am[j+0].y, s0);
    s0 = fma((double)an[j+0].z, (double)am[j+0].z, s0);
    s0 = fma((double)an[j+0].w, (double)am[j+0].w, s0);
    s1 = fma((double)an[j+1].x, (double)am[j+1].x, s1);
    s1 = fma((double)an[j+1].y, (double)am[j+1].y, s1);
    s1 = fma((double)an[j+1].z, (double)am[j+1].z, s1);
    s1 = fma((double)an[j+1].w, (double)am[j+1].w, s1);
    s2 = fma((double)an[j+2].x, (double)am[j+2].x, s2);
    s2 = fma((double)an[j+2].y, (double)am[j+2].y, s2);
    s2 = fma((double)an[j+2].z, (double)am[j+2].z, s2);
    s2 = fma((double)an[j+2].w, (double)am[j+2].w, s2);
    s3 = fma((double)an[j+3].x, (double)am[j+3].x, s3);
    s3 = fma((double)an[j+3].y, (double)am[j+3].y, s3);
    s3 = fma((double)an[j+3].z, (double)am[j+3].z, s3);
    s3 = fma((double)an[j+3].w, (double)am[j+3].w, s3);
  }
  double s = (s0 + s1) + (s2 + s3);
  s += __shfl_down(s, 2, 64);
  s += __shfl_down(s, 1, 64);                      // part==0 lanes hold full dot
  double v = 2.0*s - xxd[b*N_ + n] - xxd[b*N_ + m];
  int rank = 0;
  #pragma unroll
  for (int q = 0; q < 16; ++q){
    double vq = __shfl(v, q*4, 64);
    int    mq = __shfl(m, q*4, 64);
    bool beat = (vq > v) || ((vq == v) && (mq < m));
    rank += beat ? 1 : 0;
  }
  if (part == 0 && rank < KNb){
    idxout[(size_t)g*KNb + rank] = m;
    atomicAdd(&cnt[b*N_ + m], 1);                  // fused count (same increment set)
  }
}

// ---------------- K2: P0/D0, lane-half K-split, shuffle-combine ----------------
// R13 postmortem: VGPR 152 (128 weight floats) -> 3 waves/SIMD, 3 blocks/CU, grid
// needs 2 dispatch rounds, Occupancy 9.5%. Fix: split e in [0,96)/[96,192) across
// lane halves (lanes 0-31 / 32-63): 64 weight floats/thread -> ~100 VGPR ->
// 5 waves/SIMD -> all 1024 blocks resident (4/CU), no tail. Wave covers 32
// channels x 8 points; halves combine via 6x shfl_xor(32) per point (reg-only).
// Numerics: per-half order identical to original; one assoc join (pA+pB),
// ~1e-7 rel vs 5e-4 f16 quantum.
__global__ __launch_bounds__(256) void project_kernel(const float* __restrict__ xT,
                                                      const float* __restrict__ Wf,
                                                      const float* __restrict__ Wd,
                                                      h4* __restrict__ P0h,
                                                      h4* __restrict__ D0h){
  __shared__ float A[16 * 192];                    // 12 KB, [m][e]
  const int b = blockIdx.x, m0 = blockIdx.y * 16, t = threadIdx.x;
  const int l = t & 63, wv = t >> 6;
  const int half = l >> 5;                         // e-half
  const int c = (wv & 1)*32 + (l & 31);            // output channel
  const int mg = wv >> 1;                          // point group (8 points)

  float wfh[32], wdh[32];
  #pragma unroll
  for (int q = 0; q < 8; ++q){
    float4 uf = *(const float4*)(Wf + c*64 + half*32 + q*4);
    wfh[q*4+0]=uf.x; wfh[q*4+1]=uf.y; wfh[q*4+2]=uf.z; wfh[q*4+3]=uf.w;
    float4 ud = *(const float4*)(Wd + c*64 + half*32 + q*4);
    wdh[q*4+0]=ud.x; wdh[q*4+1]=ud.y; wdh[q*4+2]=ud.z; wdh[q*4+3]=ud.w;
  }
  {
    const float4* src = (const float4*)(xT + ((size_t)b*N_ + m0)*192);
    float4* dst = (float4*)A;
    #pragma unroll
    for (int j = 0; j < 3; ++j) dst[t + 256*j] = src[t + 256*j];
  }
  __syncthreads();

  for (int i = 0; i < 8; ++i){
    int m = mg*8 + i;
    const float4* row = (const float4*)(A + m*192 + half*96);
    float p[3] = {0.f,0.f,0.f}, qv[3] = {0.f,0.f,0.f};
    #pragma unroll
    for (int v4 = 0; v4 < 24; ++v4){
      float4 f = row[v4];
      const int e = v4*4;                          // local e within half (96%3==0)
      p [(e+0)%3] = fmaf(wfh[(e+0)/3], f.x, p [(e+0)%3]);
      qv[(e+0)%3] = fmaf(wdh[(e+0)/3], f.x, qv[(e+0)%3]);
      p [(e+1)%3] = fmaf(wfh[(e+1)/3], f.y, p [(e+1)%3]);
      qv[(e+1)%3] = fmaf(wdh[(e+1)/3], f.y, qv[(e+1)%3]);
      p [(e+2)%3] = fmaf(wfh[(e+2)/3], f.z, p [(e+2)%3]);
      qv[(e+2)%3] = fmaf(wdh[(e+2)/3], f.z, qv[(e+2)%3]);
      p [(e+3)%3] = fmaf(wfh[(e+3)/3], f.w, p [(e+3)%3]);
      qv[(e+3)%3] = fmaf(wdh[(e+3)/3], f.w, qv[(e+3)%3]);
    }
    float o0 = __shfl_xor(p[0], 32, 64), o1 = __shfl_xor(p[1], 32, 64);
    float o2 = __shfl_xor(p[2], 32, 64);
    float u0 = __shfl_xor(qv[0], 32, 64), u1 = __shfl_xor(qv[1], 32, 64);
    float u2 = __shfl_xor(qv[2], 32, 64);
    if (half == 0){
      float t0 = p[0] + o0, t1 = p[1] + o1, t2 = p[2] + o2;
      float r0 = qv[0] + u0, r1 = qv[1] + u1, r2 = qv[2] + u2;
      float nrm = sqrtf(t0*t0 + t1*t1 + t2*t2);
      float dsq = r0*r0 + r1*r1 + r2*r2;
      size_t base = ((size_t)b*N_ + m0 + m)*64 + c;
      h4 vp; vp.x = (f16)t0; vp.y = (f16)t1; vp.z = (f16)t2; vp.w = (f16)nrm;
      h4 vd; vd.x = (f16)r0; vd.y = (f16)r1; vd.z = (f16)r2; vd.w = (f16)dsq;
      P0h[base] = vp;
      D0h[base] = vd;
    }
  }
}

// ---------------- K3: per-channel weighted sum / sumsq of norms ----------------
__global__ __launch_bounds__(256) void stats_kernel(const h4* __restrict__ P0h,
                                                    const int* __restrict__ cnt,
                                                    float* __restrict__ gs){
  const int b = blockIdx.x >> 6;
  const int chunk = blockIdx.x & 63;
  const int w = threadIdx.x >> 6, c = threadIdx.x & 63;
  float s = 0.f, s2 = 0.f;
  const int mbase = chunk*32 + w*8;
  for (int i = 0; i < 8; ++i){
    int m = mbase + i;
    float wt = (float)cnt[b*N_ + m];
    float nv = (float)P0h[((size_t)b*N_ + m)*64 + c].w;
    s  = fmaf(wt, nv, s);
    s2 = fmaf(wt*nv, nv, s2);
  }
  __shared__ float red[8][64];
  red[w][c] = s; red[4+w][c] = s2;
  __syncthreads();
  if (w == 0) atomicAdd(&gs[c],    red[0][c]+red[1][c]+red[2][c]+red[3][c]);
  if (w == 1) atomicAdd(&gs[64+c], red[4][c]+red[5][c]+red[6][c]+red[7][c]);
}

// ---------------- K4: gather + BN + nonlinearity + mean over K ----------------
__global__ __launch_bounds__(512) void out_kernel(const h4* __restrict__ P0h, const h4* __restrict__ D0h,
                                                  const int* __restrict__ idxin, const float* __restrict__ gs,
                                                  const float* __restrict__ gamma, const float* __restrict__ beta,
                                                  float* __restrict__ outp){
  __shared__ float res[16 * 193];                  // 12,352 B
  const int b  = blockIdx.x;
  const int n0 = blockIdx.y * 16;
  const int t = threadIdx.x, w = t >> 6, c = t & 63;
  const float Ninv = 1.f / (float)(B_*N_*KNb);
  float mean = gs[c] * Ninv;
  float var  = gs[64+c] * Ninv - mean*mean;
  float istd = rsqrtf(var + 1e-5f);
  float sa = istd * gamma[c];
  float be = beta[c];
  const float kinv = 1.f/11.f;
  for (int i = 0; i < 2; ++i){
    int row = w*2 + i;
    int n = n0 + row;
    const int* ip = idxin + ((size_t)b*N_ + n)*KNb;
    float a0=0, a1=0, a2=0;
    #pragma unroll
    for (int k = 0; k < KNb; ++k){
      int m = ip[k] & 2047;
      size_t base = ((size_t)b*N_ + m)*64 + c;
      h4 P  = P0h[base];
      h4 Dv = D0h[base];
      float pw = (float)P.w;
      float nb = (pw - mean)*sa + be;
      float sc = nb / pw;
      float p0 = (float)P.x*sc, p1 = (float)P.y*sc, p2 = (float)P.z*sc;
      float d0 = (float)Dv.x, d1 = (float)Dv.y, d2 = (float)Dv.z;
      float dot = p0*d0 + p1*d1 + p2*d2;
      float f = (dot >= 0.f) ? 0.f : dot / ((float)Dv.w + 1e-6f);
      a0 += p0 - f*d0; a1 += p1 - f*d1; a2 += p2 - f*d2;
    }
    res[row*193 + 3*c + 0] = a0*kinv;
    res[row*193 + 3*c + 1] = a1*kinv;
    res[row*193 + 3*c + 2] = a2*kinv;
  }
  __syncthreads();
  {
    int p = t;                                     // 768 float4 stores: 512 + 256
    #pragma unroll
    for (int j = 0; j < 2; ++j){
      if (p < 768){
        int cdim = p >> 2, nq = p & 3;
        float4 v = { res[(nq*4 + 0)*193 + cdim], res[(nq*4 + 1)*193 + cdim],
                     res[(nq*4 + 2)*193 + cdim], res[(nq*4 + 3)*193 + cdim] };
        *(float4*)(outp + ((size_t)b*192 + cdim)*N_ + n0 + nq*4) = v;
      }
      p += 512;
    }
  }
}

extern "C" void kernel_launch(void* const* d_in, const int* in_sizes, int n_in,
                              void* d_out, int out_size, void* d_ws, size_t ws_size,
                              hipStream_t stream){
  const float* x     = (const float*)d_in[0];
  const float* Wf    = (const float*)d_in[1];
  const float* Wd    = (const float*)d_in[2];
  const float* gamma = (const float*)d_in[3];
  const float* beta  = (const float*)d_in[4];
  float* outp = (float*)d_out;

  char* ws = (char*)d_ws;
  int*    idx  = (int*)   (ws);                 // 720,896
  int*    cnt  = (int*)   (ws + 720896);        // 65,536
  float*  gs   = (float*) (ws + 786432);        // 512
  h4*     P0h  = (h4*)    (ws + 1048576);       // 8,388,608
  h4*     D0h  = (h4*)    (ws + 9437184);       // 8,388,608 (ends 17,825,792)
  short*  Xs   = (short*) (ws + 1048576);       //   alias (6,291,456), consumed pre-project
  double* xxd  = (double*)(ws + 13631488);      //   alias (lives in D0h region pre-project)
  u16*    cand = (u16*)   (ws + 13762560);      //   alias
  float*  xT   = (float*) (ws + 17825792);      // 12,582,912 (ends 30,408,704)

  hipMemsetAsync(cnt, 0, 66048, stream);        // zero cnt + gs (contiguous)
  split_kernel  <<<dim3(64, 8),  256, 0, stream>>>(x, Xs, xT, xxd);
  knn_kernel    <<<dim3(8, 64),  512, 0, stream>>>(Xs, xxd, cand);
  refine_kernel <<<4096,         256, 0, stream>>>(xT, cand, xxd, idx, cnt);
  project_kernel<<<dim3(8, 128), 256, 0, stream>>>(xT, Wf, Wd, P0h, D0h);
  stats_kernel  <<<512,          256, 0, stream>>>(P0h, cnt, gs);
  out_kernel    <<<dim3(8, 128), 512, 0, stream>>>(P0h, D0h, idx, gs, gamma, beta, outp);
}

// Round 15
// 228.848 us; speedup vs baseline: 1.1294x; 1.0182x over previous
//
#include <hip/hip_runtime.h>
#include <stdint.h>

#define B_   8
#define D_   192      // Cin*3
#define N_   2048
#define KNb  11       // k+1

using u32 = uint32_t;
using u16 = unsigned short;
typedef _Float16 f16;
struct alignas(8) h4 { f16 x, y, z, w; };

typedef __attribute__((ext_vector_type(8)))  short short8;
typedef __attribute__((ext_vector_type(16))) float f32x16;

__device__ __forceinline__ u16 f2bf(float f){
  union{float f; u32 i;} x; x.f = f;
  u32 r = (x.i + 0x7fffu + ((x.i >> 16) & 1u)) >> 16;
  return (u16)r;
}
__device__ __forceinline__ u32 umax32(u32 a, u32 b){ return a > b ? a : b; }
__device__ __forceinline__ u32 umin32(u32 a, u32 b){ return a < b ? a : b; }
// median-of-3 unsigned: single VOP3 op on gfx9+.
__device__ __forceinline__ u32 med3_u32(u32 a, u32 b, u32 c){
  u32 d;
  asm("v_med3_u32 %0, %1, %2, %3" : "=v"(d) : "v"(a), "v"(b), "v"(c));
  return d;
}

// branchless sorted-insert of 16 packed keys into ascending key[10], with
// wave-vote skip: ladder is a no-op unless kk > key[0] (10th best), so skip
// the whole 10-op ladder when no lane in the wave can insert (exact).
__device__ __forceinline__ void sel16(const u32* __restrict__ ctp, u32* key){
  #pragma unroll
  for (int q = 0; q < 4; ++q){
    uint4 kv = *(const uint4*)(ctp + 4*q);
    u32 ks[4] = {kv.x, kv.y, kv.z, kv.w};
    #pragma unroll
    for (int j = 0; j < 4; ++j){
      u32 kk = ks[j];
      if (__any(kk > key[0])){
        #pragma unroll
        for (int s = 0; s < 9; ++s) key[s] = med3_u32(kk, key[s], key[s+1]);
        key[9] = umax32(kk, key[9]);
      }
    }
  }
}

// ---------------- K0: bf16 fragment-page emit + fp32 transpose + f64 xx ----------------
__global__ __launch_bounds__(256) void split_kernel(const float* __restrict__ x,
                                                    short* __restrict__ Xs,
                                                    float* __restrict__ xT,
                                                    double* __restrict__ xxd){
  __shared__ float A[D_ * 32];                       // 24 KB, [d][m]
  const int b = blockIdx.y, tile = blockIdx.x, m0 = tile * 32, t = threadIdx.x;
  const size_t xb = (size_t)b * D_ * N_;
  #pragma unroll
  for (int q = 0; q < 24; ++q){
    int p = t + 256*q;
    int d = p >> 5, i = p & 31;
    A[d*32 + i] = x[xb + (size_t)d*N_ + m0 + i];
  }
  __syncthreads();

  {
    const int l = t & 63, wv = t >> 6;
    const int lh = l >> 5, l31 = l & 31;
    #pragma unroll
    for (int j = 0; j < 3; ++j){
      int c = j*4 + wv;                  // chunk 0..11
      int dbase = c*16 + lh*8;
      union{ u16 s[8]; int4 v; } u;
      #pragma unroll
      for (int q = 0; q < 8; ++q) u.s[q] = f2bf(A[(dbase + q)*32 + l31]);
      size_t P = ((size_t)b*64 + tile)*12 + c;
      *(int4*)(Xs + P*512 + l*8) = u.v;
    }
  }
  {
    const int m = t & 31, seg = t >> 5;  // 8 segs of 24 d's
    float* trow = xT + ((size_t)b*N_ + m0 + m) * 192 + seg*24;
    #pragma unroll
    for (int j = 0; j < 6; ++j){
      float4 v = { A[(seg*24 + 4*j + 0)*32 + m], A[(seg*24 + 4*j + 1)*32 + m],
                   A[(seg*24 + 4*j + 2)*32 + m], A[(seg*24 + 4*j + 3)*32 + m] };
      *(float4*)(trow + 4*j) = v;
    }
  }
  if (t < 32){
    double s = 0.0;
    #pragma unroll 4
    for (int d = 0; d < D_; ++d){ double v = (double)A[d*32 + t]; s = fma(v, v, s); }
    xxd[b*N_ + m0 + t] = s;
  }
}

// ---------------- K1: MFMA kNN: reg prefetch + med3+vote select + in-wave merge ----------------
// R14 postmortem: merge was a serial tail (32 threads, 256 dependent LDS reads);
// selection ladder ran even when un-insertable. Fix: (a) remap selection threads
// (r = t>>4, g = t&15) so each row's 16 sorted lists live in ONE wave -> merge is
// a register/shuffle pop loop across all 512 threads, MVK deleted; (b) __any-vote
// skip in sel16. Keys embed m in low bits -> unique -> merge order/set unchanged.
#define KLA   0         // 12,288 : A pages
#define KLCT0 12288     // u32[32*260] = 33,280 (buffer 0)
#define KLCT1 45568     // u32[32*260] = 33,280 (buffer 1)
#define KLSZ  78848
__global__ __launch_bounds__(512, 4) void knn_kernel(const short* __restrict__ Xs,
                                                     const double* __restrict__ xxd,
                                                     u16* __restrict__ cand){
  __shared__ __align__(16) char smem[KLSZ];

  const int b = blockIdx.x, n0 = blockIdx.y * 32;
  const int t = threadIdx.x, lane = t & 63, w = t >> 6;
  const int l31 = lane & 31, lh = lane >> 5;
  const int mcol = w*32 + l31;
  const int selr = t >> 4, selg = t & 15;          // selection/merge mapping

  // stage A (12 pages = query tile n0>>5)
  {
    const short* Ap = Xs + (((size_t)b*64 + (n0 >> 5)) * 12) * 512;
    int4 v = *(const int4*)(Ap + (size_t)t*8);
    *(int4*)(smem + KLA + t*16) = v;
    if (t < 256){
      int p = t + 512;
      int4 v2 = *(const int4*)(Ap + (size_t)p*8);
      *(int4*)(smem + KLA + p*16) = v2;
    }
  }
  // query-row norms in registers (constant over stripes)
  float xxn[16];
  #pragma unroll
  for (int reg = 0; reg < 16; ++reg){
    int r = (reg & 3) + 8*(reg >> 2) + 4*lh;
    xxn[reg] = (float)xxd[b*N_ + n0 + r];
  }
  __syncthreads();                                 // A staged

  u32 key[10];
  #pragma unroll
  for (int j = 0; j < 10; ++j) key[j] = 0u;

  for (int st = 0; st < 8; ++st){
    const int m0 = st * 256;
    // wave w consumes neighbor tile st*8+w: issue ALL 12 page loads up front
    const short* Bp = Xs + (((size_t)b*64 + st*8 + w) * 12) * 512 + lane*8;
    short8 pg[12];
    #pragma unroll
    for (int j = 0; j < 12; ++j) pg[j] = *(const short8*)(Bp + j*512);
    float xxs = (float)xxd[b*N_ + m0 + mcol];

    // selection of previous stripe overlaps the load flight above
    if (st > 0){
      const u32* ctp = (const u32*)(smem + ((st & 1) ? KLCT0 : KLCT1))
                       + selr*260 + selg*16;
      sel16(ctp, key);
    }

    f32x16 acc = (f32x16)0.0f;
    #pragma unroll
    for (int kc = 0; kc < 6; ++kc){
      short8 a0 = *(const short8*)(smem + KLA + (kc*2+0)*1024 + lane*16);
      short8 a1 = *(const short8*)(smem + KLA + (kc*2+1)*1024 + lane*16);
      acc = __builtin_amdgcn_mfma_f32_32x32x16_bf16(a0, pg[kc*2+0], acc, 0, 0, 0);
      acc = __builtin_amdgcn_mfma_f32_32x32x16_bf16(a1, pg[kc*2+1], acc, 0, 0, 0);
    }

    // pack keys in registers, write to this stripe's buffer
    {
      u32* ctw = (u32*)(smem + ((st & 1) ? KLCT1 : KLCT0));
      const u32 midx = (u32)(m0 + mcol);
      #pragma unroll
      for (int reg = 0; reg < 16; ++reg){
        float v = fmaf(2.f, acc[reg], -(xxs + xxn[reg]));
        u32 bb = __float_as_uint(v);
        u32 kk = ((bb ^ (u32)(((int)bb >> 31) | 0x80000000)) & 0xFFFFF800u) | midx;
        int r = (reg & 3) + 8*(reg >> 2) + 4*lh;
        ctw[r*260 + mcol] = kk;
      }
    }
    __syncthreads();                               // one barrier per stripe
  }
  // final stripe's selection (stripe 7 wrote KLCT1)
  {
    const u32* ctp = (const u32*)(smem + KLCT1) + selr*260 + selg*16;
    sel16(ctp, key);
  }

  // in-wave merge: each row's 16 sorted lists are in one wave (lanes (selr&3)*16+g).
  // 16 rounds: butterfly-max of heads over the 16-lane group, winner pops (unique
  // keys -> exactly one winner), lane g==s records round s. Register-only.
  {
    u32 mycand = 0u;
    #pragma unroll
    for (int s = 0; s < 16; ++s){
      u32 h = key[9];
      u32 wm = h;
      #pragma unroll
      for (int d = 1; d < 16; d <<= 1) wm = umax32(wm, __shfl_xor(wm, d, 16));
      bool win = (h == wm);
      #pragma unroll
      for (int q = 9; q > 0; --q) key[q] = win ? key[q-1] : key[q];
      key[0] = win ? 0u : key[0];
      mycand = (selg == s) ? wm : mycand;
    }
    cand[((size_t)b*N_ + n0 + selr)*16 + selg] = (u16)(mycand & 2047u);
  }
}

// ---------------- K1b: f64 refine + fused counting, XCD-pinned, staged MLP ----------------
__global__ __launch_bounds__(256, 3) void refine_kernel(const float* __restrict__ xT,
                                                        const u16* __restrict__ cand,
                                                        const double* __restrict__ xxd,
                                                        int* __restrict__ idxout,
                                                        int* __restrict__ cnt){
  const int wv = threadIdx.x >> 6, ln = threadIdx.x & 63;
  const int b = blockIdx.x & 7;                    // XCD-pinned batch
  const int n = (blockIdx.x >> 3) * 4 + wv;        // 0..2047
  const int g = b * N_ + n;
  const int c = ln >> 2, part = ln & 3;
  const int m = (int)cand[(size_t)g*16 + c] & 2047;
  const float4* pn = (const float4*)(xT + ((size_t)b*N_ + n)*192 + part*48);
  const float4* pm = (const float4*)(xT + ((size_t)b*N_ + m)*192 + part*48);
  float4 an[12], am[12];
  #pragma unroll
  for (int j = 0; j < 12; ++j) an[j] = pn[j];
  #pragma unroll
  for (int j = 0; j < 12; ++j) am[j] = pm[j];
  double s0 = 0.0, s1 = 0.0, s2 = 0.0, s3 = 0.0;
  #pragma unroll
  for (int j = 0; j < 12; j += 4){
    s0 = fma((double)an[j+0].x, (double)am[j+0].x, s0);
    s0 = fma((double)an[j+0].y, (double)am[j+0].y, s0);
    s0 = fma((double)an[j+0].z, (double)am[j+0].z, s0);
    s0 = fma((double)an[j+0].w, (double)am[j+0].w, s0);
    s1 = fma((double)an[j+1].x, (double)am[j+1].x, s1);
    s1 = fma((double)an[j+1].y, (double)am[j+1].y, s1);
    s1 = fma((double)an[j+1].z, (double)am[j+1].z, s1);
    s1 = fma((double)an[j+1].w, (double)am[j+1].w, s1);
    s2 = fma((double)an[j+2].x, (double)am[j+2].x, s2);
    s2 = fma((double)an[j+2].y, (double)am[j+2].y, s2);
    s2 = fma((double)an[j+2].z, (double)am[j+2].z, s2);
    s2 = fma((double)an[j+2].w, (double)am[j+2].w, s2);
    s3 = fma((double)an[j+3].x, (double)am[j+3].x, s3);
    s3 = fma((double)an[j+3].y, (double)am[j+3].y, s3);
    s3 = fma((double)an[j+3].z, (double)am[j+3].z, s3);
    s3 = fma((double)an[j+3].w, (double)am[j+3].w, s3);
  }
  double s = (s0 + s1) + (s2 + s3);
  s += __shfl_down(s, 2, 64);
  s += __shfl_down(s, 1, 64);                      // part==0 lanes hold full dot
  double v = 2.0*s - xxd[b*N_ + n] - xxd[b*N_ + m];
  int rank = 0;
  #pragma unroll
  for (int q = 0; q < 16; ++q){
    double vq = __shfl(v, q*4, 64);
    int    mq = __shfl(m, q*4, 64);
    bool beat = (vq > v) || ((vq == v) && (mq < m));
    rank += beat ? 1 : 0;
  }
  if (part == 0 && rank < KNb){
    idxout[(size_t)g*KNb + rank] = m;
    atomicAdd(&cnt[b*N_ + m], 1);                  // fused count (same increment set)
  }
}

// ---------------- K2: P0/D0, lane-half K-split, shuffle-combine ----------------
__global__ __launch_bounds__(256) void project_kernel(const float* __restrict__ xT,
                                                      const float* __restrict__ Wf,
                                                      const float* __restrict__ Wd,
                                                      h4* __restrict__ P0h,
                                                      h4* __restrict__ D0h){
  __shared__ float A[16 * 192];                    // 12 KB, [m][e]
  const int b = blockIdx.x, m0 = blockIdx.y * 16, t = threadIdx.x;
  const int l = t & 63, wv = t >> 6;
  const int half = l >> 5;                         // e-half
  const int c = (wv & 1)*32 + (l & 31);            // output channel
  const int mg = wv >> 1;                          // point group (8 points)

  float wfh[32], wdh[32];
  #pragma unroll
  for (int q = 0; q < 8; ++q){
    float4 uf = *(const float4*)(Wf + c*64 + half*32 + q*4);
    wfh[q*4+0]=uf.x; wfh[q*4+1]=uf.y; wfh[q*4+2]=uf.z; wfh[q*4+3]=uf.w;
    float4 ud = *(const float4*)(Wd + c*64 + half*32 + q*4);
    wdh[q*4+0]=ud.x; wdh[q*4+1]=ud.y; wdh[q*4+2]=ud.z; wdh[q*4+3]=ud.w;
  }
  {
    const float4* src = (const float4*)(xT + ((size_t)b*N_ + m0)*192);
    float4* dst = (float4*)A;
    #pragma unroll
    for (int j = 0; j < 3; ++j) dst[t + 256*j] = src[t + 256*j];
  }
  __syncthreads();

  for (int i = 0; i < 8; ++i){
    int m = mg*8 + i;
    const float4* row = (const float4*)(A + m*192 + half*96);
    float p[3] = {0.f,0.f,0.f}, qv[3] = {0.f,0.f,0.f};
    #pragma unroll
    for (int v4 = 0; v4 < 24; ++v4){
      float4 f = row[v4];
      const int e = v4*4;                          // local e within half (96%3==0)
      p [(e+0)%3] = fmaf(wfh[(e+0)/3], f.x, p [(e+0)%3]);
      qv[(e+0)%3] = fmaf(wdh[(e+0)/3], f.x, qv[(e+0)%3]);
      p [(e+1)%3] = fmaf(wfh[(e+1)/3], f.y, p [(e+1)%3]);
      qv[(e+1)%3] = fmaf(wdh[(e+1)/3], f.y, qv[(e+1)%3]);
      p [(e+2)%3] = fmaf(wfh[(e+2)/3], f.z, p [(e+2)%3]);
      qv[(e+2)%3] = fmaf(wdh[(e+2)/3], f.z, qv[(e+2)%3]);
      p [(e+3)%3] = fmaf(wfh[(e+3)/3], f.w, p [(e+3)%3]);
      qv[(e+3)%3] = fmaf(wdh[(e+3)/3], f.w, qv[(e+3)%3]);
    }
    float o0 = __shfl_xor(p[0], 32, 64), o1 = __shfl_xor(p[1], 32, 64);
    float o2 = __shfl_xor(p[2], 32, 64);
    float u0 = __shfl_xor(qv[0], 32, 64), u1 = __shfl_xor(qv[1], 32, 64);
    float u2 = __shfl_xor(qv[2], 32, 64);
    if (half == 0){
      float t0 = p[0] + o0, t1 = p[1] + o1, t2 = p[2] + o2;
      float r0 = qv[0] + u0, r1 = qv[1] + u1, r2 = qv[2] + u2;
      float nrm = sqrtf(t0*t0 + t1*t1 + t2*t2);
      float dsq = r0*r0 + r1*r1 + r2*r2;
      size_t base = ((size_t)b*N_ + m0 + m)*64 + c;
      h4 vp; vp.x = (f16)t0; vp.y = (f16)t1; vp.z = (f16)t2; vp.w = (f16)nrm;
      h4 vd; vd.x = (f16)r0; vd.y = (f16)r1; vd.z = (f16)r2; vd.w = (f16)dsq;
      P0h[base] = vp;
      D0h[base] = vd;
    }
  }
}

// ---------------- K3: per-channel weighted sum / sumsq of norms ----------------
__global__ __launch_bounds__(256) void stats_kernel(const h4* __restrict__ P0h,
                                                    const int* __restrict__ cnt,
                                                    float* __restrict__ gs){
  const int b = blockIdx.x >> 6;
  const int chunk = blockIdx.x & 63;
  const int w = threadIdx.x >> 6, c = threadIdx.x & 63;
  float s = 0.f, s2 = 0.f;
  const int mbase = chunk*32 + w*8;
  for (int i = 0; i < 8; ++i){
    int m = mbase + i;
    float wt = (float)cnt[b*N_ + m];
    float nv = (float)P0h[((size_t)b*N_ + m)*64 + c].w;
    s  = fmaf(wt, nv, s);
    s2 = fmaf(wt*nv, nv, s2);
  }
  __shared__ float red[8][64];
  red[w][c] = s; red[4+w][c] = s2;
  __syncthreads();
  if (w == 0) atomicAdd(&gs[c],    red[0][c]+red[1][c]+red[2][c]+red[3][c]);
  if (w == 1) atomicAdd(&gs[64+c], red[4][c]+red[5][c]+red[6][c]+red[7][c]);
}

// ---------------- K4: gather + BN + nonlinearity + mean over K ----------------
__global__ __launch_bounds__(512) void out_kernel(const h4* __restrict__ P0h, const h4* __restrict__ D0h,
                                                  const int* __restrict__ idxin, const float* __restrict__ gs,
                                                  const float* __restrict__ gamma, const float* __restrict__ beta,
                                                  float* __restrict__ outp){
  __shared__ float res[16 * 193];                  // 12,352 B
  const int b  = blockIdx.x;
  const int n0 = blockIdx.y * 16;
  const int t = threadIdx.x, w = t >> 6, c = t & 63;
  const float Ninv = 1.f / (float)(B_*N_*KNb);
  float mean = gs[c] * Ninv;
  float var  = gs[64+c] * Ninv - mean*mean;
  float istd = rsqrtf(var + 1e-5f);
  float sa = istd * gamma[c];
  float be = beta[c];
  const float kinv = 1.f/11.f;
  for (int i = 0; i < 2; ++i){
    int row = w*2 + i;
    int n = n0 + row;
    const int* ip = idxin + ((size_t)b*N_ + n)*KNb;
    float a0=0, a1=0, a2=0;
    #pragma unroll
    for (int k = 0; k < KNb; ++k){
      int m = ip[k] & 2047;
      size_t base = ((size_t)b*N_ + m)*64 + c;
      h4 P  = P0h[base];
      h4 Dv = D0h[base];
      float pw = (float)P.w;
      float nb = (pw - mean)*sa + be;
      float sc = nb / pw;
      float p0 = (float)P.x*sc, p1 = (float)P.y*sc, p2 = (float)P.z*sc;
      float d0 = (float)Dv.x, d1 = (float)Dv.y, d2 = (float)Dv.z;
      float dot = p0*d0 + p1*d1 + p2*d2;
      float f = (dot >= 0.f) ? 0.f : dot / ((float)Dv.w + 1e-6f);
      a0 += p0 - f*d0; a1 += p1 - f*d1; a2 += p2 - f*d2;
    }
    res[row*193 + 3*c + 0] = a0*kinv;
    res[row*193 + 3*c + 1] = a1*kinv;
    res[row*193 + 3*c + 2] = a2*kinv;
  }
  __syncthreads();
  {
    int p = t;                                     // 768 float4 stores: 512 + 256
    #pragma unroll
    for (int j = 0; j < 2; ++j){
      if (p < 768){
        int cdim = p >> 2, nq = p & 3;
        float4 v = { res[(nq*4 + 0)*193 + cdim], res[(nq*4 + 1)*193 + cdim],
                     res[(nq*4 + 2)*193 + cdim], res[(nq*4 + 3)*193 + cdim] };
        *(float4*)(outp + ((size_t)b*192 + cdim)*N_ + n0 + nq*4) = v;
      }
      p += 512;
    }
  }
}

extern "C" void kernel_launch(void* const* d_in, const int* in_sizes, int n_in,
                              void* d_out, int out_size, void* d_ws, size_t ws_size,
                              hipStream_t stream){
  const float* x     = (const float*)d_in[0];
  const float* Wf    = (const float*)d_in[1];
  const float* Wd    = (const float*)d_in[2];
  const float* gamma = (const float*)d_in[3];
  const float* beta  = (const float*)d_in[4];
  float* outp = (float*)d_out;

  char* ws = (char*)d_ws;
  int*    idx  = (int*)   (ws);                 // 720,896
  int*    cnt  = (int*)   (ws + 720896);        // 65,536
  float*  gs   = (float*) (ws + 786432);        // 512
  h4*     P0h  = (h4*)    (ws + 1048576);       // 8,388,608
  h4*     D0h  = (h4*)    (ws + 9437184);       // 8,388,608 (ends 17,825,792)
  short*  Xs   = (short*) (ws + 1048576);       //   alias (6,291,456), consumed pre-project
  double* xxd  = (double*)(ws + 13631488);      //   alias (lives in D0h region pre-project)
  u16*    cand = (u16*)   (ws + 13762560);      //   alias
  float*  xT   = (float*) (ws + 17825792);      // 12,582,912 (ends 30,408,704)

  hipMemsetAsync(cnt, 0, 66048, stream);        // zero cnt + gs (contiguous)
  split_kernel  <<<dim3(64, 8),  256, 0, stream>>>(x, Xs, xT, xxd);
  knn_kernel    <<<dim3(8, 64),  512, 0, stream>>>(Xs, xxd, cand);
  refine_kernel <<<4096,         256, 0, stream>>>(xT, cand, xxd, idx, cnt);
  project_kernel<<<dim3(8, 128), 256, 0, stream>>>(xT, Wf, Wd, P0h, D0h);
  stats_kernel  <<<512,          256, 0, stream>>>(P0h, cnt, gs);
  out_kernel    <<<dim3(8, 128), 512, 0, stream>>>(P0h, D0h, idx, gs, gamma, beta, outp);
}

// Round 17
// 217.533 us; speedup vs baseline: 1.1881x; 1.0520x over previous
//
#include <hip/hip_runtime.h>
#include <stdint.h>

#define B_   8
#define D_   192      // Cin*3
#define N_   2048
#define KNb  11       // k+1

using u32 = uint32_t;
using u16 = unsigned short;
typedef _Float16 f16;
struct alignas(8) h4 { f16 x, y, z, w; };

typedef __attribute__((ext_vector_type(8)))  short short8;
typedef __attribute__((ext_vector_type(16))) float f32x16;
typedef __attribute__((ext_vector_type(4)))  float f32x4;

__device__ __forceinline__ u16 f2bf(float f){
  union{float f; u32 i;} x; x.f = f;
  u32 r = (x.i + 0x7fffu + ((x.i >> 16) & 1u)) >> 16;
  return (u16)r;
}
__device__ __forceinline__ u32 umax32(u32 a, u32 b){ return a > b ? a : b; }
__device__ __forceinline__ u32 umin32(u32 a, u32 b){ return a < b ? a : b; }
// median-of-3 unsigned: single VOP3 op on gfx9+.
__device__ __forceinline__ u32 med3_u32(u32 a, u32 b, u32 c){
  u32 d;
  asm("v_med3_u32 %0, %1, %2, %3" : "=v"(d) : "v"(a), "v"(b), "v"(c));
  return d;
}

// branchless sorted-insert of 16 packed keys into ascending key[10], with
// wave-vote skip (exact: ladder is a no-op unless kk > key[0]).
__device__ __forceinline__ void sel16(const u32* __restrict__ ctp, u32* key){
  #pragma unroll
  for (int q = 0; q < 4; ++q){
    uint4 kv = *(const uint4*)(ctp + 4*q);
    u32 ks[4] = {kv.x, kv.y, kv.z, kv.w};
    #pragma unroll
    for (int j = 0; j < 4; ++j){
      u32 kk = ks[j];
      if (__any(kk > key[0])){
        #pragma unroll
        for (int s = 0; s < 9; ++s) key[s] = med3_u32(kk, key[s], key[s+1]);
        key[9] = umax32(kk, key[9]);
      }
    }
  }
}

// ---------------- K0: bf16 fragment-page emit + fp32 transpose + f64 xx ----------------
__global__ __launch_bounds__(256) void split_kernel(const float* __restrict__ x,
                                                    short* __restrict__ Xs,
                                                    float* __restrict__ xT,
                                                    double* __restrict__ xxd){
  __shared__ float A[D_ * 32];                       // 24 KB, [d][m]
  const int b = blockIdx.y, tile = blockIdx.x, m0 = tile * 32, t = threadIdx.x;
  const size_t xb = (size_t)b * D_ * N_;
  #pragma unroll
  for (int q = 0; q < 24; ++q){
    int p = t + 256*q;
    int d = p >> 5, i = p & 31;
    A[d*32 + i] = x[xb + (size_t)d*N_ + m0 + i];
  }
  __syncthreads();

  {
    const int l = t & 63, wv = t >> 6;
    const int lh = l >> 5, l31 = l & 31;
    #pragma unroll
    for (int j = 0; j < 3; ++j){
      int c = j*4 + wv;                  // chunk 0..11
      int dbase = c*16 + lh*8;
      union{ u16 s[8]; int4 v; } u;
      #pragma unroll
      for (int q = 0; q < 8; ++q) u.s[q] = f2bf(A[(dbase + q)*32 + l31]);
      size_t P = ((size_t)b*64 + tile)*12 + c;
      *(int4*)(Xs + P*512 + l*8) = u.v;
    }
  }
  {
    const int m = t & 31, seg = t >> 5;  // 8 segs of 24 d's
    float* trow = xT + ((size_t)b*N_ + m0 + m) * 192 + seg*24;
    #pragma unroll
    for (int j = 0; j < 6; ++j){
      float4 v = { A[(seg*24 + 4*j + 0)*32 + m], A[(seg*24 + 4*j + 1)*32 + m],
                   A[(seg*24 + 4*j + 2)*32 + m], A[(seg*24 + 4*j + 3)*32 + m] };
      *(float4*)(trow + 4*j) = v;
    }
  }
  if (t < 32){
    double s = 0.0;
    #pragma unroll 4
    for (int d = 0; d < D_; ++d){ double v = (double)A[d*32 + t]; s = fma(v, v, s); }
    xxd[b*N_ + m0 + t] = s;
  }
}

// ---------------- K1: MFMA kNN: reg prefetch + med3+vote select + in-wave merge ----------------
#define KLA   0         // 12,288 : A pages
#define KLCT0 12288     // u32[32*260] = 33,280 (buffer 0)
#define KLCT1 45568     // u32[32*260] = 33,280 (buffer 1)
#define KLSZ  78848
__global__ __launch_bounds__(512, 4) void knn_kernel(const short* __restrict__ Xs,
                                                     const double* __restrict__ xxd,
                                                     u16* __restrict__ cand){
  __shared__ __align__(16) char smem[KLSZ];

  const int b = blockIdx.x, n0 = blockIdx.y * 32;
  const int t = threadIdx.x, lane = t & 63, w = t >> 6;
  const int l31 = lane & 31, lh = lane >> 5;
  const int mcol = w*32 + l31;
  const int selr = t >> 4, selg = t & 15;          // selection/merge mapping

  // stage A (12 pages = query tile n0>>5)
  {
    const short* Ap = Xs + (((size_t)b*64 + (n0 >> 5)) * 12) * 512;
    int4 v = *(const int4*)(Ap + (size_t)t*8);
    *(int4*)(smem + KLA + t*16) = v;
    if (t < 256){
      int p = t + 512;
      int4 v2 = *(const int4*)(Ap + (size_t)p*8);
      *(int4*)(smem + KLA + p*16) = v2;
    }
  }
  // query-row norms in registers (constant over stripes)
  float xxn[16];
  #pragma unroll
  for (int reg = 0; reg < 16; ++reg){
    int r = (reg & 3) + 8*(reg >> 2) + 4*lh;
    xxn[reg] = (float)xxd[b*N_ + n0 + r];
  }
  __syncthreads();                                 // A staged

  u32 key[10];
  #pragma unroll
  for (int j = 0; j < 10; ++j) key[j] = 0u;

  for (int st = 0; st < 8; ++st){
    const int m0 = st * 256;
    // wave w consumes neighbor tile st*8+w: issue ALL 12 page loads up front
    const short* Bp = Xs + (((size_t)b*64 + st*8 + w) * 12) * 512 + lane*8;
    short8 pg[12];
    #pragma unroll
    for (int j = 0; j < 12; ++j) pg[j] = *(const short8*)(Bp + j*512);
    float xxs = (float)xxd[b*N_ + m0 + mcol];

    // selection of previous stripe overlaps the load flight above
    if (st > 0){
      const u32* ctp = (const u32*)(smem + ((st & 1) ? KLCT0 : KLCT1))
                       + selr*260 + selg*16;
      sel16(ctp, key);
    }

    f32x16 acc = (f32x16)0.0f;
    #pragma unroll
    for (int kc = 0; kc < 6; ++kc){
      short8 a0 = *(const short8*)(smem + KLA + (kc*2+0)*1024 + lane*16);
      short8 a1 = *(const short8*)(smem + KLA + (kc*2+1)*1024 + lane*16);
      acc = __builtin_amdgcn_mfma_f32_32x32x16_bf16(a0, pg[kc*2+0], acc, 0, 0, 0);
      acc = __builtin_amdgcn_mfma_f32_32x32x16_bf16(a1, pg[kc*2+1], acc, 0, 0, 0);
    }

    // pack keys in registers, write to this stripe's buffer
    {
      u32* ctw = (u32*)(smem + ((st & 1) ? KLCT1 : KLCT0));
      const u32 midx = (u32)(m0 + mcol);
      #pragma unroll
      for (int reg = 0; reg < 16; ++reg){
        float v = fmaf(2.f, acc[reg], -(xxs + xxn[reg]));
        u32 bb = __float_as_uint(v);
        u32 kk = ((bb ^ (u32)(((int)bb >> 31) | 0x80000000)) & 0xFFFFF800u) | midx;
        int r = (reg & 3) + 8*(reg >> 2) + 4*lh;
        ctw[r*260 + mcol] = kk;
      }
    }
    __syncthreads();                               // one barrier per stripe
  }
  // final stripe's selection (stripe 7 wrote KLCT1)
  {
    const u32* ctp = (const u32*)(smem + KLCT1) + selr*260 + selg*16;
    sel16(ctp, key);
  }

  // in-wave merge: 16 rounds of 16-lane butterfly-max pop (keys unique).
  {
    u32 mycand = 0u;
    #pragma unroll
    for (int s = 0; s < 16; ++s){
      u32 h = key[9];
      u32 wm = h;
      #pragma unroll
      for (int d = 1; d < 16; d <<= 1) wm = umax32(wm, __shfl_xor(wm, d, 16));
      bool win = (h == wm);
      #pragma unroll
      for (int q = 9; q > 0; --q) key[q] = win ? key[q-1] : key[q];
      key[0] = win ? 0u : key[0];
      mycand = (selg == s) ? wm : mycand;
    }
    cand[((size_t)b*N_ + n0 + selr)*16 + selg] = (u16)(mycand & 2047u);
  }
}

// ---------------- K1b: f64 refine + fused counting, XCD-pinned, barrier-forced MLP ----------------
// R15 postmortem: (256,3) alone didn't stop load-sinking (VGPR 40, 12 serial
// latency rounds). R16's hand-asm loads may have broken the build. De-risked:
// plain C++ loads (compiler-tracked vmcnt) + ONE empty asm volatile tying all 24
// loaded values "+v" -> all loads must issue before it, values forced live
// (96 VGPR) -> single latency exposure. sched_barrier(0) pins the fma block after.
__global__ __launch_bounds__(256, 3) void refine_kernel(const float* __restrict__ xT,
                                                        const u16* __restrict__ cand,
                                                        const double* __restrict__ xxd,
                                                        int* __restrict__ idxout,
                                                        int* __restrict__ cnt){
  const int wv = threadIdx.x >> 6, ln = threadIdx.x & 63;
  const int b = blockIdx.x & 7;                    // XCD-pinned batch
  const int n = (blockIdx.x >> 3) * 4 + wv;        // 0..2047
  const int g = b * N_ + n;
  const int c = ln >> 2, part = ln & 3;
  const int m = (int)cand[(size_t)g*16 + c] & 2047;
  const f32x4* pn = (const f32x4*)(xT + ((size_t)b*N_ + n)*192 + part*48);
  const f32x4* pm = (const f32x4*)(xT + ((size_t)b*N_ + m)*192 + part*48);
  f32x4 an[12], am[12];
  #pragma unroll
  for (int j = 0; j < 12; ++j) an[j] = pn[j];
  #pragma unroll
  for (int j = 0; j < 12; ++j) am[j] = pm[j];
  asm volatile(""
    : "+v"(an[0]), "+v"(an[1]), "+v"(an[2]),  "+v"(an[3]),  "+v"(an[4]),  "+v"(an[5]),
      "+v"(an[6]), "+v"(an[7]), "+v"(an[8]),  "+v"(an[9]),  "+v"(an[10]), "+v"(an[11]),
      "+v"(am[0]), "+v"(am[1]), "+v"(am[2]),  "+v"(am[3]),  "+v"(am[4]),  "+v"(am[5]),
      "+v"(am[6]), "+v"(am[7]), "+v"(am[8]),  "+v"(am[9]),  "+v"(am[10]), "+v"(am[11]));
  __builtin_amdgcn_sched_barrier(0);

  double s0 = 0.0, s1 = 0.0, s2 = 0.0, s3 = 0.0;
  #pragma unroll
  for (int j = 0; j < 12; j += 4){
    s0 = fma((double)an[j+0][0], (double)am[j+0][0], s0);
    s0 = fma((double)an[j+0][1], (double)am[j+0][1], s0);
    s0 = fma((double)an[j+0][2], (double)am[j+0][2], s0);
    s0 = fma((double)an[j+0][3], (double)am[j+0][3], s0);
    s1 = fma((double)an[j+1][0], (double)am[j+1][0], s1);
    s1 = fma((double)an[j+1][1], (double)am[j+1][1], s1);
    s1 = fma((double)an[j+1][2], (double)am[j+1][2], s1);
    s1 = fma((double)an[j+1][3], (double)am[j+1][3], s1);
    s2 = fma((double)an[j+2][0], (double)am[j+2][0], s2);
    s2 = fma((double)an[j+2][1], (double)am[j+2][1], s2);
    s2 = fma((double)an[j+2][2], (double)am[j+2][2], s2);
    s2 = fma((double)an[j+2][3], (double)am[j+2][3], s2);
    s3 = fma((double)an[j+3][0], (double)am[j+3][0], s3);
    s3 = fma((double)an[j+3][1], (double)am[j+3][1], s3);
    s3 = fma((double)an[j+3][2], (double)am[j+3][2], s3);
    s3 = fma((double)an[j+3][3], (double)am[j+3][3], s3);
  }
  double s = (s0 + s1) + (s2 + s3);
  s += __shfl_down(s, 2, 64);
  s += __shfl_down(s, 1, 64);                      // part==0 lanes hold full dot
  double v = 2.0*s - xxd[b*N_ + n] - xxd[b*N_ + m];
  int rank = 0;
  #pragma unroll
  for (int q = 0; q < 16; ++q){
    double vq = __shfl(v, q*4, 64);
    int    mq = __shfl(m, q*4, 64);
    bool beat = (vq > v) || ((vq == v) && (mq < m));
    rank += beat ? 1 : 0;
  }
  if (part == 0 && rank < KNb){
    idxout[(size_t)g*KNb + rank] = m;
    atomicAdd(&cnt[b*N_ + m], 1);                  // fused count (same increment set)
  }
}

// ---------------- K2: P0/D0, lane-half K-split, shuffle-combine ----------------
__global__ __launch_bounds__(256) void project_kernel(const float* __restrict__ xT,
                                                      const float* __restrict__ Wf,
                                                      const float* __restrict__ Wd,
                                                      h4* __restrict__ P0h,
                                                      h4* __restrict__ D0h){
  __shared__ float A[16 * 192];                    // 12 KB, [m][e]
  const int b = blockIdx.x, m0 = blockIdx.y * 16, t = threadIdx.x;
  const int l = t & 63, wv = t >> 6;
  const int half = l >> 5;                         // e-half
  const int c = (wv & 1)*32 + (l & 31);            // output channel
  const int mg = wv >> 1;                          // point group (8 points)

  float wfh[32], wdh[32];
  #pragma unroll
  for (int q = 0; q < 8; ++q){
    float4 uf = *(const float4*)(Wf + c*64 + half*32 + q*4);
    wfh[q*4+0]=uf.x; wfh[q*4+1]=uf.y; wfh[q*4+2]=uf.z; wfh[q*4+3]=uf.w;
    float4 ud = *(const float4*)(Wd + c*64 + half*32 + q*4);
    wdh[q*4+0]=ud.x; wdh[q*4+1]=ud.y; wdh[q*4+2]=ud.z; wdh[q*4+3]=ud.w;
  }
  {
    const float4* src = (const float4*)(xT + ((size_t)b*N_ + m0)*192);
    float4* dst = (float4*)A;
    #pragma unroll
    for (int j = 0; j < 3; ++j) dst[t + 256*j] = src[t + 256*j];
  }
  __syncthreads();

  for (int i = 0; i < 8; ++i){
    int m = mg*8 + i;
    const float4* row = (const float4*)(A + m*192 + half*96);
    float p[3] = {0.f,0.f,0.f}, qv[3] = {0.f,0.f,0.f};
    #pragma unroll
    for (int v4 = 0; v4 < 24; ++v4){
      float4 f = row[v4];
      const int e = v4*4;                          // local e within half (96%3==0)
      p [(e+0)%3] = fmaf(wfh[(e+0)/3], f.x, p [(e+0)%3]);
      qv[(e+0)%3] = fmaf(wdh[(e+0)/3], f.x, qv[(e+0)%3]);
      p [(e+1)%3] = fmaf(wfh[(e+1)/3], f.y, p [(e+1)%3]);
      qv[(e+1)%3] = fmaf(wdh[(e+1)/3], f.y, qv[(e+1)%3]);
      p [(e+2)%3] = fmaf(wfh[(e+2)/3], f.z, p [(e+2)%3]);
      qv[(e+2)%3] = fmaf(wdh[(e+2)/3], f.z, qv[(e+2)%3]);
      p [(e+3)%3] = fmaf(wfh[(e+3)/3], f.w, p [(e+3)%3]);
      qv[(e+3)%3] = fmaf(wdh[(e+3)/3], f.w, qv[(e+3)%3]);
    }
    float o0 = __shfl_xor(p[0], 32, 64), o1 = __shfl_xor(p[1], 32, 64);
    float o2 = __shfl_xor(p[2], 32, 64);
    float u0 = __shfl_xor(qv[0], 32, 64), u1 = __shfl_xor(qv[1], 32, 64);
    float u2 = __shfl_xor(qv[2], 32, 64);
    if (half == 0){
      float t0 = p[0] + o0, t1 = p[1] + o1, t2 = p[2] + o2;
      float r0 = qv[0] + u0, r1 = qv[1] + u1, r2 = qv[2] + u2;
      float nrm = sqrtf(t0*t0 + t1*t1 + t2*t2);
      float dsq = r0*r0 + r1*r1 + r2*r2;
      size_t base = ((size_t)b*N_ + m0 + m)*64 + c;
      h4 vp; vp.x = (f16)t0; vp.y = (f16)t1; vp.z = (f16)t2; vp.w = (f16)nrm;
      h4 vd; vd.x = (f16)r0; vd.y = (f16)r1; vd.z = (f16)r2; vd.w = (f16)dsq;
      P0h[base] = vp;
      D0h[base] = vd;
    }
  }
}

// ---------------- K3: per-channel weighted sum / sumsq of norms ----------------
__global__ __launch_bounds__(256) void stats_kernel(const h4* __restrict__ P0h,
                                                    const int* __restrict__ cnt,
                                                    float* __restrict__ gs){
  const int b = blockIdx.x >> 6;
  const int chunk = blockIdx.x & 63;
  const int w = threadIdx.x >> 6, c = threadIdx.x & 63;
  float s = 0.f, s2 = 0.f;
  const int mbase = chunk*32 + w*8;
  for (int i = 0; i < 8; ++i){
    int m = mbase + i;
    float wt = (float)cnt[b*N_ + m];
    float nv = (float)P0h[((size_t)b*N_ + m)*64 + c].w;
    s  = fmaf(wt, nv, s);
    s2 = fmaf(wt*nv, nv, s2);
  }
  __shared__ float red[8][64];
  red[w][c] = s; red[4+w][c] = s2;
  __syncthreads();
  if (w == 0) atomicAdd(&gs[c],    red[0][c]+red[1][c]+red[2][c]+red[3][c]);
  if (w == 1) atomicAdd(&gs[64+c], red[4][c]+red[5][c]+red[6][c]+red[7][c]);
}

// ---------------- K4: gather + BN + nonlinearity + mean over K ----------------
__global__ __launch_bounds__(512) void out_kernel(const h4* __restrict__ P0h, const h4* __restrict__ D0h,
                                                  const int* __restrict__ idxin, const float* __restrict__ gs,
                                                  const float* __restrict__ gamma, const float* __restrict__ beta,
                                                  float* __restrict__ outp){
  __shared__ float res[16 * 193];                  // 12,352 B
  const int b  = blockIdx.x;
  const int n0 = blockIdx.y * 16;
  const int t = threadIdx.x, w = t >> 6, c = t & 63;
  const float Ninv = 1.f / (float)(B_*N_*KNb);
  float mean = gs[c] * Ninv;
  float var  = gs[64+c] * Ninv - mean*mean;
  float istd = rsqrtf(var + 1e-5f);
  float sa = istd * gamma[c];
  float be = beta[c];
  const float kinv = 1.f/11.f;
  for (int i = 0; i < 2; ++i){
    int row = w*2 + i;
    int n = n0 + row;
    const int* ip = idxin + ((size_t)b*N_ + n)*KNb;
    float a0=0, a1=0, a2=0;
    #pragma unroll
    for (int k = 0; k < KNb; ++k){
      int m = ip[k] & 2047;
      size_t base = ((size_t)b*N_ + m)*64 + c;
      h4 P  = P0h[base];
      h4 Dv = D0h[base];
      float pw = (float)P.w;
      float nb = (pw - mean)*sa + be;
      float sc = nb / pw;
      float p0 = (float)P.x*sc, p1 = (float)P.y*sc, p2 = (float)P.z*sc;
      float d0 = (float)Dv.x, d1 = (float)Dv.y, d2 = (float)Dv.z;
      float dot = p0*d0 + p1*d1 + p2*d2;
      float f = (dot >= 0.f) ? 0.f : dot / ((float)Dv.w + 1e-6f);
      a0 += p0 - f*d0; a1 += p1 - f*d1; a2 += p2 - f*d2;
    }
    res[row*193 + 3*c + 0] = a0*kinv;
    res[row*193 + 3*c + 1] = a1*kinv;
    res[row*193 + 3*c + 2] = a2*kinv;
  }
  __syncthreads();
  {
    int p = t;                                     // 768 float4 stores: 512 + 256
    #pragma unroll
    for (int j = 0; j < 2; ++j){
      if (p < 768){
        int cdim = p >> 2, nq = p & 3;
        float4 v = { res[(nq*4 + 0)*193 + cdim], res[(nq*4 + 1)*193 + cdim],
                     res[(nq*4 + 2)*193 + cdim], res[(nq*4 + 3)*193 + cdim] };
        *(float4*)(outp + ((size_t)b*192 + cdim)*N_ + n0 + nq*4) = v;
      }
      p += 512;
    }
  }
}

extern "C" void kernel_launch(void* const* d_in, const int* in_sizes, int n_in,
                              void* d_out, int out_size, void* d_ws, size_t ws_size,
                              hipStream_t stream){
  const float* x     = (const float*)d_in[0];
  const float* Wf    = (const float*)d_in[1];
  const float* Wd    = (const float*)d_in[2];
  const float* gamma = (const float*)d_in[3];
  const float* beta  = (const float*)d_in[4];
  float* outp = (float*)d_out;

  char* ws = (char*)d_ws;
  int*    idx  = (int*)   (ws);                 // 720,896
  int*    cnt  = (int*)   (ws + 720896);        // 65,536
  float*  gs   = (float*) (ws + 786432);        // 512
  h4*     P0h  = (h4*)    (ws + 1048576);       // 8,388,608
  h4*     D0h  = (h4*)    (ws + 9437184);       // 8,388,608 (ends 17,825,792)
  short*  Xs   = (short*) (ws + 1048576);       //   alias (6,291,456), consumed pre-project
  double* xxd  = (double*)(ws + 13631488);      //   alias (lives in D0h region pre-project)
  u16*    cand = (u16*)   (ws + 13762560);      //   alias
  float*  xT   = (float*) (ws + 17825792);      // 12,582,912 (ends 30,408,704)

  hipMemsetAsync(cnt, 0, 66048, stream);        // zero cnt + gs (contiguous)
  split_kernel  <<<dim3(64, 8),  256, 0, stream>>>(x, Xs, xT, xxd);
  knn_kernel    <<<dim3(8, 64),  512, 0, stream>>>(Xs, xxd, cand);
  refine_kernel <<<4096,         256, 0, stream>>>(xT, cand, xxd, idx, cnt);
  project_kernel<<<dim3(8, 128), 256, 0, stream>>>(xT, Wf, Wd, P0h, D0h);
  stats_kernel  <<<512,          256, 0, stream>>>(P0h, cnt, gs);
  out_kernel    <<<dim3(8, 128), 512, 0, stream>>>(P0h, D0h, idx, gs, gamma, beta, outp);
}

// Round 18
// 216.263 us; speedup vs baseline: 1.1951x; 1.0059x over previous
//
#include <hip/hip_runtime.h>
#include <stdint.h>

#define B_   8
#define D_   192      // Cin*3
#define N_   2048
#define KNb  11       // k+1

using u32 = uint32_t;
using u16 = unsigned short;
typedef _Float16 f16;
struct alignas(8) h4 { f16 x, y, z, w; };

typedef __attribute__((ext_vector_type(8)))  short short8;
typedef __attribute__((ext_vector_type(16))) float f32x16;
typedef __attribute__((ext_vector_type(4)))  float f32x4;

__device__ __forceinline__ u16 f2bf(float f){
  union{float f; u32 i;} x; x.f = f;
  u32 r = (x.i + 0x7fffu + ((x.i >> 16) & 1u)) >> 16;
  return (u16)r;
}
__device__ __forceinline__ u32 umax32(u32 a, u32 b){ return a > b ? a : b; }
__device__ __forceinline__ u32 umin32(u32 a, u32 b){ return a < b ? a : b; }
// median-of-3 unsigned: single VOP3 op on gfx9+.
__device__ __forceinline__ u32 med3_u32(u32 a, u32 b, u32 c){
  u32 d;
  asm("v_med3_u32 %0, %1, %2, %3" : "=v"(d) : "v"(a), "v"(b), "v"(c));
  return d;
}

// branchless sorted-insert of 16 packed keys into ascending key[10], with
// wave-vote skip (exact: ladder is a no-op unless kk > key[0]).
__device__ __forceinline__ void sel16(const u32* __restrict__ ctp, u32* key){
  #pragma unroll
  for (int q = 0; q < 4; ++q){
    uint4 kv = *(const uint4*)(ctp + 4*q);
    u32 ks[4] = {kv.x, kv.y, kv.z, kv.w};
    #pragma unroll
    for (int j = 0; j < 4; ++j){
      u32 kk = ks[j];
      if (__any(kk > key[0])){
        #pragma unroll
        for (int s = 0; s < 9; ++s) key[s] = med3_u32(kk, key[s], key[s+1]);
        key[9] = umax32(kk, key[9]);
      }
    }
  }
}

// ---------------- K0: bf16 fragment-page emit + fp32 transpose + f64 xx ----------------
__global__ __launch_bounds__(256) void split_kernel(const float* __restrict__ x,
                                                    short* __restrict__ Xs,
                                                    float* __restrict__ xT,
                                                    double* __restrict__ xxd){
  __shared__ float A[D_ * 32];                       // 24 KB, [d][m]
  const int b = blockIdx.y, tile = blockIdx.x, m0 = tile * 32, t = threadIdx.x;
  const size_t xb = (size_t)b * D_ * N_;
  #pragma unroll
  for (int q = 0; q < 24; ++q){
    int p = t + 256*q;
    int d = p >> 5, i = p & 31;
    A[d*32 + i] = x[xb + (size_t)d*N_ + m0 + i];
  }
  __syncthreads();

  {
    const int l = t & 63, wv = t >> 6;
    const int lh = l >> 5, l31 = l & 31;
    #pragma unroll
    for (int j = 0; j < 3; ++j){
      int c = j*4 + wv;                  // chunk 0..11
      int dbase = c*16 + lh*8;
      union{ u16 s[8]; int4 v; } u;
      #pragma unroll
      for (int q = 0; q < 8; ++q) u.s[q] = f2bf(A[(dbase + q)*32 + l31]);
      size_t P = ((size_t)b*64 + tile)*12 + c;
      *(int4*)(Xs + P*512 + l*8) = u.v;
    }
  }
  {
    const int m = t & 31, seg = t >> 5;  // 8 segs of 24 d's
    float* trow = xT + ((size_t)b*N_ + m0 + m) * 192 + seg*24;
    #pragma unroll
    for (int j = 0; j < 6; ++j){
      float4 v = { A[(seg*24 + 4*j + 0)*32 + m], A[(seg*24 + 4*j + 1)*32 + m],
                   A[(seg*24 + 4*j + 2)*32 + m], A[(seg*24 + 4*j + 3)*32 + m] };
      *(float4*)(trow + 4*j) = v;
    }
  }
  if (t < 32){
    double s = 0.0;
    #pragma unroll 4
    for (int d = 0; d < D_; ++d){ double v = (double)A[d*32 + t]; s = fma(v, v, s); }
    xxd[b*N_ + m0 + t] = s;
  }
}

// ---------------- K1: MFMA kNN: cross-stripe prefetch + med3+vote select + in-wave merge ----------------
// R17 state: all kernels <42us; knn largest (~40). Residual serial chain: stripe's
// first MFMA waits on pg[0] with only sel16 (~300cy) covering ~200-400cy L2 latency,
// paid barrier-aligned by all 16 waves. Fix: prefetch first 4 pages of stripe st+1
// into pre0..3 AFTER the MFMA loop (acc-phase peak stays ~110 VGPR < 128 cap) ->
// ~550cy flight over keypack+barrier+sel16. Remaining 8 pages keep stripe-start
// issue (first needed at kc=2, +150cy extra cover).
#define KLA   0         // 12,288 : A pages
#define KLCT0 12288     // u32[32*260] = 33,280 (buffer 0)
#define KLCT1 45568     // u32[32*260] = 33,280 (buffer 1)
#define KLSZ  78848
__global__ __launch_bounds__(512, 4) void knn_kernel(const short* __restrict__ Xs,
                                                     const double* __restrict__ xxd,
                                                     u16* __restrict__ cand){
  __shared__ __align__(16) char smem[KLSZ];

  const int b = blockIdx.x, n0 = blockIdx.y * 32;
  const int t = threadIdx.x, lane = t & 63, w = t >> 6;
  const int l31 = lane & 31, lh = lane >> 5;
  const int mcol = w*32 + l31;
  const int selr = t >> 4, selg = t & 15;          // selection/merge mapping

  // stage A (12 pages = query tile n0>>5)
  {
    const short* Ap = Xs + (((size_t)b*64 + (n0 >> 5)) * 12) * 512;
    int4 v = *(const int4*)(Ap + (size_t)t*8);
    *(int4*)(smem + KLA + t*16) = v;
    if (t < 256){
      int p = t + 512;
      int4 v2 = *(const int4*)(Ap + (size_t)p*8);
      *(int4*)(smem + KLA + p*16) = v2;
    }
  }
  // query-row norms in registers (constant over stripes)
  float xxn[16];
  #pragma unroll
  for (int reg = 0; reg < 16; ++reg){
    int r = (reg & 3) + 8*(reg >> 2) + 4*lh;
    xxn[reg] = (float)xxd[b*N_ + n0 + r];
  }
  __syncthreads();                                 // A staged

  u32 key[10];
  #pragma unroll
  for (int j = 0; j < 10; ++j) key[j] = 0u;

  short8 pre0, pre1, pre2, pre3;                   // next-stripe prefetch (pages 0-3)

  for (int st = 0; st < 8; ++st){
    const int m0 = st * 256;
    // wave w consumes neighbor tile st*8+w
    const short* Bp = Xs + (((size_t)b*64 + st*8 + w) * 12) * 512 + lane*8;
    short8 pg[12];
    if (st == 0){
      pg[0] = *(const short8*)(Bp + 0*512);
      pg[1] = *(const short8*)(Bp + 1*512);
      pg[2] = *(const short8*)(Bp + 2*512);
      pg[3] = *(const short8*)(Bp + 3*512);
    } else {
      pg[0] = pre0; pg[1] = pre1; pg[2] = pre2; pg[3] = pre3;
    }
    #pragma unroll
    for (int j = 4; j < 12; ++j) pg[j] = *(const short8*)(Bp + j*512);
    float xxs = (float)xxd[b*N_ + m0 + mcol];

    // selection of previous stripe overlaps the load flight above
    if (st > 0){
      const u32* ctp = (const u32*)(smem + ((st & 1) ? KLCT0 : KLCT1))
                       + selr*260 + selg*16;
      sel16(ctp, key);
    }

    f32x16 acc = (f32x16)0.0f;
    #pragma unroll
    for (int kc = 0; kc < 6; ++kc){
      short8 a0 = *(const short8*)(smem + KLA + (kc*2+0)*1024 + lane*16);
      short8 a1 = *(const short8*)(smem + KLA + (kc*2+1)*1024 + lane*16);
      acc = __builtin_amdgcn_mfma_f32_32x32x16_bf16(a0, pg[kc*2+0], acc, 0, 0, 0);
      acc = __builtin_amdgcn_mfma_f32_32x32x16_bf16(a1, pg[kc*2+1], acc, 0, 0, 0);
    }

    // prefetch first 4 pages of next stripe (same wave -> +8 tiles = +49152 shorts);
    // ~550cy flight across keypack+barrier+sel16 before first use.
    if (st < 7){
      const short* Bn = Bp + 8 * 12 * 512;
      pre0 = *(const short8*)(Bn + 0*512);
      pre1 = *(const short8*)(Bn + 1*512);
      pre2 = *(const short8*)(Bn + 2*512);
      pre3 = *(const short8*)(Bn + 3*512);
    }

    // pack keys in registers, write to this stripe's buffer
    {
      u32* ctw = (u32*)(smem + ((st & 1) ? KLCT1 : KLCT0));
      const u32 midx = (u32)(m0 + mcol);
      #pragma unroll
      for (int reg = 0; reg < 16; ++reg){
        float v = fmaf(2.f, acc[reg], -(xxs + xxn[reg]));
        u32 bb = __float_as_uint(v);
        u32 kk = ((bb ^ (u32)(((int)bb >> 31) | 0x80000000)) & 0xFFFFF800u) | midx;
        int r = (reg & 3) + 8*(reg >> 2) + 4*lh;
        ctw[r*260 + mcol] = kk;
      }
    }
    __syncthreads();                               // one barrier per stripe
  }
  // final stripe's selection (stripe 7 wrote KLCT1)
  {
    const u32* ctp = (const u32*)(smem + KLCT1) + selr*260 + selg*16;
    sel16(ctp, key);
  }

  // in-wave merge: 16 rounds of 16-lane butterfly-max pop (keys unique).
  {
    u32 mycand = 0u;
    #pragma unroll
    for (int s = 0; s < 16; ++s){
      u32 h = key[9];
      u32 wm = h;
      #pragma unroll
      for (int d = 1; d < 16; d <<= 1) wm = umax32(wm, __shfl_xor(wm, d, 16));
      bool win = (h == wm);
      #pragma unroll
      for (int q = 9; q > 0; --q) key[q] = win ? key[q-1] : key[q];
      key[0] = win ? 0u : key[0];
      mycand = (selg == s) ? wm : mycand;
    }
    cand[((size_t)b*N_ + n0 + selr)*16 + selg] = (u16)(mycand & 2047u);
  }
}

// ---------------- K1b: f64 refine + fused counting, XCD-pinned, barrier-forced MLP ----------------
__global__ __launch_bounds__(256, 3) void refine_kernel(const float* __restrict__ xT,
                                                        const u16* __restrict__ cand,
                                                        const double* __restrict__ xxd,
                                                        int* __restrict__ idxout,
                                                        int* __restrict__ cnt){
  const int wv = threadIdx.x >> 6, ln = threadIdx.x & 63;
  const int b = blockIdx.x & 7;                    // XCD-pinned batch
  const int n = (blockIdx.x >> 3) * 4 + wv;        // 0..2047
  const int g = b * N_ + n;
  const int c = ln >> 2, part = ln & 3;
  const int m = (int)cand[(size_t)g*16 + c] & 2047;
  const f32x4* pn = (const f32x4*)(xT + ((size_t)b*N_ + n)*192 + part*48);
  const f32x4* pm = (const f32x4*)(xT + ((size_t)b*N_ + m)*192 + part*48);
  f32x4 an[12], am[12];
  #pragma unroll
  for (int j = 0; j < 12; ++j) an[j] = pn[j];
  #pragma unroll
  for (int j = 0; j < 12; ++j) am[j] = pm[j];
  asm volatile(""
    : "+v"(an[0]), "+v"(an[1]), "+v"(an[2]),  "+v"(an[3]),  "+v"(an[4]),  "+v"(an[5]),
      "+v"(an[6]), "+v"(an[7]), "+v"(an[8]),  "+v"(an[9]),  "+v"(an[10]), "+v"(an[11]),
      "+v"(am[0]), "+v"(am[1]), "+v"(am[2]),  "+v"(am[3]),  "+v"(am[4]),  "+v"(am[5]),
      "+v"(am[6]), "+v"(am[7]), "+v"(am[8]),  "+v"(am[9]),  "+v"(am[10]), "+v"(am[11]));
  __builtin_amdgcn_sched_barrier(0);

  double s0 = 0.0, s1 = 0.0, s2 = 0.0, s3 = 0.0;
  #pragma unroll
  for (int j = 0; j < 12; j += 4){
    s0 = fma((double)an[j+0][0], (double)am[j+0][0], s0);
    s0 = fma((double)an[j+0][1], (double)am[j+0][1], s0);
    s0 = fma((double)an[j+0][2], (double)am[j+0][2], s0);
    s0 = fma((double)an[j+0][3], (double)am[j+0][3], s0);
    s1 = fma((double)an[j+1][0], (double)am[j+1][0], s1);
    s1 = fma((double)an[j+1][1], (double)am[j+1][1], s1);
    s1 = fma((double)an[j+1][2], (double)am[j+1][2], s1);
    s1 = fma((double)an[j+1][3], (double)am[j+1][3], s1);
    s2 = fma((double)an[j+2][0], (double)am[j+2][0], s2);
    s2 = fma((double)an[j+2][1], (double)am[j+2][1], s2);
    s2 = fma((double)an[j+2][2], (double)am[j+2][2], s2);
    s2 = fma((double)an[j+2][3], (double)am[j+2][3], s2);
    s3 = fma((double)an[j+3][0], (double)am[j+3][0], s3);
    s3 = fma((double)an[j+3][1], (double)am[j+3][1], s3);
    s3 = fma((double)an[j+3][2], (double)am[j+3][2], s3);
    s3 = fma((double)an[j+3][3], (double)am[j+3][3], s3);
  }
  double s = (s0 + s1) + (s2 + s3);
  s += __shfl_down(s, 2, 64);
  s += __shfl_down(s, 1, 64);                      // part==0 lanes hold full dot
  double v = 2.0*s - xxd[b*N_ + n] - xxd[b*N_ + m];
  int rank = 0;
  #pragma unroll
  for (int q = 0; q < 16; ++q){
    double vq = __shfl(v, q*4, 64);
    int    mq = __shfl(m, q*4, 64);
    bool beat = (vq > v) || ((vq == v) && (mq < m));
    rank += beat ? 1 : 0;
  }
  if (part == 0 && rank < KNb){
    idxout[(size_t)g*KNb + rank] = m;
    atomicAdd(&cnt[b*N_ + m], 1);                  // fused count (same increment set)
  }
}

// ---------------- K2: P0/D0, lane-half K-split, shuffle-combine ----------------
__global__ __launch_bounds__(256) void project_kernel(const float* __restrict__ xT,
                                                      const float* __restrict__ Wf,
                                                      const float* __restrict__ Wd,
                                                      h4* __restrict__ P0h,
                                                      h4* __restrict__ D0h){
  __shared__ float A[16 * 192];                    // 12 KB, [m][e]
  const int b = blockIdx.x, m0 = blockIdx.y * 16, t = threadIdx.x;
  const int l = t & 63, wv = t >> 6;
  const int half = l >> 5;                         // e-half
  const int c = (wv & 1)*32 + (l & 31);            // output channel
  const int mg = wv >> 1;                          // point group (8 points)

  float wfh[32], wdh[32];
  #pragma unroll
  for (int q = 0; q < 8; ++q){
    float4 uf = *(const float4*)(Wf + c*64 + half*32 + q*4);
    wfh[q*4+0]=uf.x; wfh[q*4+1]=uf.y; wfh[q*4+2]=uf.z; wfh[q*4+3]=uf.w;
    float4 ud = *(const float4*)(Wd + c*64 + half*32 + q*4);
    wdh[q*4+0]=ud.x; wdh[q*4+1]=ud.y; wdh[q*4+2]=ud.z; wdh[q*4+3]=ud.w;
  }
  {
    const float4* src = (const float4*)(xT + ((size_t)b*N_ + m0)*192);
    float4* dst = (float4*)A;
    #pragma unroll
    for (int j = 0; j < 3; ++j) dst[t + 256*j] = src[t + 256*j];
  }
  __syncthreads();

  for (int i = 0; i < 8; ++i){
    int m = mg*8 + i;
    const float4* row = (const float4*)(A + m*192 + half*96);
    float p[3] = {0.f,0.f,0.f}, qv[3] = {0.f,0.f,0.f};
    #pragma unroll
    for (int v4 = 0; v4 < 24; ++v4){
      float4 f = row[v4];
      const int e = v4*4;                          // local e within half (96%3==0)
      p [(e+0)%3] = fmaf(wfh[(e+0)/3], f.x, p [(e+0)%3]);
      qv[(e+0)%3] = fmaf(wdh[(e+0)/3], f.x, qv[(e+0)%3]);
      p [(e+1)%3] = fmaf(wfh[(e+1)/3], f.y, p [(e+1)%3]);
      qv[(e+1)%3] = fmaf(wdh[(e+1)/3], f.y, qv[(e+1)%3]);
      p [(e+2)%3] = fmaf(wfh[(e+2)/3], f.z, p [(e+2)%3]);
      qv[(e+2)%3] = fmaf(wdh[(e+2)/3], f.z, qv[(e+2)%3]);
      p [(e+3)%3] = fmaf(wfh[(e+3)/3], f.w, p [(e+3)%3]);
      qv[(e+3)%3] = fmaf(wdh[(e+3)/3], f.w, qv[(e+3)%3]);
    }
    float o0 = __shfl_xor(p[0], 32, 64), o1 = __shfl_xor(p[1], 32, 64);
    float o2 = __shfl_xor(p[2], 32, 64);
    float u0 = __shfl_xor(qv[0], 32, 64), u1 = __shfl_xor(qv[1], 32, 64);
    float u2 = __shfl_xor(qv[2], 32, 64);
    if (half == 0){
      float t0 = p[0] + o0, t1 = p[1] + o1, t2 = p[2] + o2;
      float r0 = qv[0] + u0, r1 = qv[1] + u1, r2 = qv[2] + u2;
      float nrm = sqrtf(t0*t0 + t1*t1 + t2*t2);
      float dsq = r0*r0 + r1*r1 + r2*r2;
      size_t base = ((size_t)b*N_ + m0 + m)*64 + c;
      h4 vp; vp.x = (f16)t0; vp.y = (f16)t1; vp.z = (f16)t2; vp.w = (f16)nrm;
      h4 vd; vd.x = (f16)r0; vd.y = (f16)r1; vd.z = (f16)r2; vd.w = (f16)dsq;
      P0h[base] = vp;
      D0h[base] = vd;
    }
  }
}

// ---------------- K3: per-channel weighted sum / sumsq of norms ----------------
__global__ __launch_bounds__(256) void stats_kernel(const h4* __restrict__ P0h,
                                                    const int* __restrict__ cnt,
                                                    float* __restrict__ gs){
  const int b = blockIdx.x >> 6;
  const int chunk = blockIdx.x & 63;
  const int w = threadIdx.x >> 6, c = threadIdx.x & 63;
  float s = 0.f, s2 = 0.f;
  const int mbase = chunk*32 + w*8;
  for (int i = 0; i < 8; ++i){
    int m = mbase + i;
    float wt = (float)cnt[b*N_ + m];
    float nv = (float)P0h[((size_t)b*N_ + m)*64 + c].w;
    s  = fmaf(wt, nv, s);
    s2 = fmaf(wt*nv, nv, s2);
  }
  __shared__ float red[8][64];
  red[w][c] = s; red[4+w][c] = s2;
  __syncthreads();
  if (w == 0) atomicAdd(&gs[c],    red[0][c]+red[1][c]+red[2][c]+red[3][c]);
  if (w == 1) atomicAdd(&gs[64+c], red[4][c]+red[5][c]+red[6][c]+red[7][c]);
}

// ---------------- K4: gather + BN + nonlinearity + mean over K ----------------
__global__ __launch_bounds__(512) void out_kernel(const h4* __restrict__ P0h, const h4* __restrict__ D0h,
                                                  const int* __restrict__ idxin, const float* __restrict__ gs,
                                                  const float* __restrict__ gamma, const float* __restrict__ beta,
                                                  float* __restrict__ outp){
  __shared__ float res[16 * 193];                  // 12,352 B
  const int b  = blockIdx.x;
  const int n0 = blockIdx.y * 16;
  const int t = threadIdx.x, w = t >> 6, c = t & 63;
  const float Ninv = 1.f / (float)(B_*N_*KNb);
  float mean = gs[c] * Ninv;
  float var  = gs[64+c] * Ninv - mean*mean;
  float istd = rsqrtf(var + 1e-5f);
  float sa = istd * gamma[c];
  float be = beta[c];
  const float kinv = 1.f/11.f;
  for (int i = 0; i < 2; ++i){
    int row = w*2 + i;
    int n = n0 + row;
    const int* ip = idxin + ((size_t)b*N_ + n)*KNb;
    float a0=0, a1=0, a2=0;
    #pragma unroll
    for (int k = 0; k < KNb; ++k){
      int m = ip[k] & 2047;
      size_t base = ((size_t)b*N_ + m)*64 + c;
      h4 P  = P0h[base];
      h4 Dv = D0h[base];
      float pw = (float)P.w;
      float nb = (pw - mean)*sa + be;
      float sc = nb / pw;
      float p0 = (float)P.x*sc, p1 = (float)P.y*sc, p2 = (float)P.z*sc;
      float d0 = (float)Dv.x, d1 = (float)Dv.y, d2 = (float)Dv.z;
      float dot = p0*d0 + p1*d1 + p2*d2;
      float f = (dot >= 0.f) ? 0.f : dot / ((float)Dv.w + 1e-6f);
      a0 += p0 - f*d0; a1 += p1 - f*d1; a2 += p2 - f*d2;
    }
    res[row*193 + 3*c + 0] = a0*kinv;
    res[row*193 + 3*c + 1] = a1*kinv;
    res[row*193 + 3*c + 2] = a2*kinv;
  }
  __syncthreads();
  {
    int p = t;                                     // 768 float4 stores: 512 + 256
    #pragma unroll
    for (int j = 0; j < 2; ++j){
      if (p < 768){
        int cdim = p >> 2, nq = p & 3;
        float4 v = { res[(nq*4 + 0)*193 + cdim], res[(nq*4 + 1)*193 + cdim],
                     res[(nq*4 + 2)*193 + cdim], res[(nq*4 + 3)*193 + cdim] };
        *(float4*)(outp + ((size_t)b*192 + cdim)*N_ + n0 + nq*4) = v;
      }
      p += 512;
    }
  }
}

extern "C" void kernel_launch(void* const* d_in, const int* in_sizes, int n_in,
                              void* d_out, int out_size, void* d_ws, size_t ws_size,
                              hipStream_t stream){
  const float* x     = (const float*)d_in[0];
  const float* Wf    = (const float*)d_in[1];
  const float* Wd    = (const float*)d_in[2];
  const float* gamma = (const float*)d_in[3];
  const float* beta  = (const float*)d_in[4];
  float* outp = (float*)d_out;

  char* ws = (char*)d_ws;
  int*    idx  = (int*)   (ws);                 // 720,896
  int*    cnt  = (int*)   (ws + 720896);        // 65,536
  float*  gs   = (float*) (ws + 786432);        // 512
  h4*     P0h  = (h4*)    (ws + 1048576);       // 8,388,608
  h4*     D0h  = (h4*)    (ws + 9437184);       // 8,388,608 (ends 17,825,792)
  short*  Xs   = (short*) (ws + 1048576);       //   alias (6,291,456), consumed pre-project
  double* xxd  = (double*)(ws + 13631488);      //   alias (lives in D0h region pre-project)
  u16*    cand = (u16*)   (ws + 13762560);      //   alias
  float*  xT   = (float*) (ws + 17825792);      // 12,582,912 (ends 30,408,704)

  hipMemsetAsync(cnt, 0, 66048, stream);        // zero cnt + gs (contiguous)
  split_kernel  <<<dim3(64, 8),  256, 0, stream>>>(x, Xs, xT, xxd);
  knn_kernel    <<<dim3(8, 64),  512, 0, stream>>>(Xs, xxd, cand);
  refine_kernel <<<4096,         256, 0, stream>>>(xT, cand, xxd, idx, cnt);
  project_kernel<<<dim3(8, 128), 256, 0, stream>>>(xT, Wf, Wd, P0h, D0h);
  stats_kernel  <<<512,          256, 0, stream>>>(P0h, cnt, gs);
  out_kernel    <<<dim3(8, 128), 512, 0, stream>>>(P0h, D0h, idx, gs, gamma, beta, outp);
}